// Round 13
// baseline (142.647 us; speedup 1.0000x reference)
//
#include <hip/hip_runtime.h>
#include <hip/hip_bf16.h>
#include <math.h>

#define NPIX   16384
#define BATCH  8
#define BN_EPS 1e-5f
#define EPS_V  1e-6f

typedef __attribute__((ext_vector_type(8))) short bf16x8;
typedef __attribute__((ext_vector_type(4))) float f32x4;
typedef const __attribute__((address_space(1))) unsigned int* gas_ptr;
typedef __attribute__((address_space(3))) unsigned int* las_ptr;

// ---- workspace layout (float offsets) ----
#define OFF_K     ((size_t)0)          // fallback: Kbuf. mfma path: wxbr + part2
#define OFF_PART2 ((size_t)8192)       // mfma: 512*2192 = 1122304 (ends 1130496 < 2097152)
#define OFF_W1F   ((size_t)2097152)    // 128*32   = 4096
#define OFF_WKT   ((size_t)2101248)    // 128*16   = 2048
#define OFF_WVT   ((size_t)2103296)    // 128*128  = 16384
#define OFF_BF    ((size_t)2119680)    // 4*32     = 128
#define OFF_PART  ((size_t)2119808)    // 512*2192 = 1122304
#define OFF_STATS ((size_t)3242112)    // 8*2192   = 17536
#define BASE_END  ((size_t)3259648)
// mfma path extras
#define OFF_WBT   BASE_END             // 3*9*4*2*64*8 ushort = 55296 floats
#define OFF_XT    ((size_t)3314976)    // 8*4*16384*32 ushort = 8388608 floats (PRE-SWIZZLED)
#define OFF_WVB   ((size_t)11703584)   // 4*8*64*8 ushort = 8192 floats
#define OFF_ZROW  ((size_t)11711776)   // 4096 ushort zero row = 2048 floats
#define NEW_END   ((size_t)11713824)
// fallback extras
#define OFF_W24T  BASE_END             // 3*128*9*32 = 110592

__device__ inline unsigned short f2bf(float f) {
  union { float f; unsigned int u; } v; v.f = f;
  unsigned int r = (v.u + 0x7FFFu + ((v.u >> 16) & 1u)) >> 16;
  return (unsigned short)r;
}

// ---------------- prep_common (fallback path only) ----------------
__global__ void prep_common_kernel(const float* __restrict__ w1,
                                   const float* __restrict__ bns, const float* __restrict__ bnb,
                                   const float* __restrict__ bnm, const float* __restrict__ bnv,
                                   const float* __restrict__ wk, const float* __restrict__ wv,
                                   float* __restrict__ w1f, float* __restrict__ wkt,
                                   float* __restrict__ wvt, float* __restrict__ bf) {
  int tid = blockIdx.x * blockDim.x + threadIdx.x;
  int nt  = gridDim.x * blockDim.x;
  for (int i = tid; i < 128; i += nt) {
    float inv = bns[i] * rsqrtf(bnv[i] + BN_EPS);
    bf[i] = bnb[i] - bnm[i] * inv;
  }
  for (int i = tid; i < 4096; i += nt) {          // w1f[c][o]
    int c = i >> 5, o = i & 31;
    float inv = bns[o] * rsqrtf(bnv[o] + BN_EPS);
    w1f[i] = w1[o * 128 + c] * inv;
  }
  for (int i = tid; i < 2048; i += nt) {          // wkt[c][m]
    int c = i >> 4, m = i & 15;
    wkt[i] = wk[m * 128 + c];
  }
  for (int i = tid; i < 16384; i += nt) {         // wvt[c][o]
    int c = i >> 7, o = i & 127;
    wvt[i] = wv[o * 128 + c];
  }
}

// ---------------- pa0: merged a0 (blocks 0..2047) + prep_convb (blocks 2048..2111) ----------------
__global__ __launch_bounds__(256) void pa0_kernel(const float* __restrict__ x,
                                                  unsigned short* __restrict__ xt,
                                                  const float* __restrict__ w1,
                                                  const float* __restrict__ w2,
                                                  const float* __restrict__ w3,
                                                  const float* __restrict__ w4,
                                                  const float* __restrict__ bns,
                                                  const float* __restrict__ bnb,
                                                  const float* __restrict__ bnm,
                                                  const float* __restrict__ bnv,
                                                  const float* __restrict__ wk,
                                                  const float* __restrict__ wv,
                                                  unsigned short* __restrict__ wbtr,
                                                  unsigned short* __restrict__ wvbr,
                                                  unsigned short* __restrict__ wxbr,
                                                  unsigned short* __restrict__ zrow,
                                                  float* __restrict__ bf) {
  __shared__ unsigned short Ts[64][132];
  int t   = threadIdx.x;
  int idx = blockIdx.x;
  if (idx < 2048) {
    // ---- a0: transpose x -> xt bf16, quarter-major, pre-swizzled 16B units ----
    int b   = idx & 7;                  // batch -> XCD spread
    int px0 = (idx >> 3) * 64;
    const float* xb = x + (size_t)b * 128 * NPIX;
    int p = t & 63, cq = t >> 6;
#pragma unroll 8
    for (int i = 0; i < 32; ++i) {
      int c = cq * 32 + i;
      Ts[p][c] = f2bf(xb[(size_t)c * NPIX + px0 + p]);
    }
    __syncthreads();
    int pw = t >> 2, cg = t & 3;        // cg == quarter
    unsigned short* dst = xt + ((size_t)(b * 4 + cg) * 16384 + px0 + pw) * 32;
    int sw = (pw >> 1) & 3;
#pragma unroll
    for (int k = 0; k < 8; ++k) {
      uint2 v = *(const uint2*)(&Ts[pw][cg * 32 + k * 4]);
      int cgs = (k >> 1) ^ sw;
      *(uint2*)(dst + cgs * 8 + (k & 1) * 4) = v;
    }
  } else {
    // ---- prep_convb (grid-stride over 64 virtual blocks) ----
    int tid = (idx - 2048) * 256 + t;
    int nt  = 64 * 256;
    for (int i = tid; i < 128; i += nt) {
      float inv = bns[i] * rsqrtf(bnv[i] + BN_EPS);
      bf[i] = bnb[i] - bnm[i] * inv;
    }
    for (int i = tid; i < 4096; i += nt) zrow[i] = 0;
    for (int i = tid; i < 16384; i += nt) {
      int e = i & 7, lane = (i >> 3) & 63, f = (i >> 9) & 7, q = i >> 12;
      int oc = f * 16 + (lane & 15);
      int c  = q * 32 + (lane >> 4) * 8 + e;
      wvbr[i] = f2bf(wv[oc * 128 + c]);
    }
    for (int i = tid; i < 6144; i += nt) {
      int e = i & 7, lane = (i >> 3) & 63, ct = i >> 9;
      int tile = ct % 3, q = ct / 3;
      int c = q * 32 + (lane >> 4) * 8 + e;
      float val;
      if (tile < 2) {
        int oc = tile * 16 + (lane & 15);
        val = w1[oc * 128 + c] * (bns[oc] * rsqrtf(bnv[oc] + BN_EPS));
      } else {
        val = wk[(lane & 15) * 128 + c];
      }
      wxbr[i] = f2bf(val);
    }
    for (int i = tid; i < 110592; i += nt) {
      int br = i / 36864;
      int r  = i - br * 36864;
      int tap  = r >> 12;
      int r2   = r & 4095;
      int q    = r2 >> 10;
      int r3   = r2 & 1023;
      int pair = r3 >> 9;
      int r4   = r3 & 511;
      int lane = r4 >> 3, e = r4 & 7;
      int oc = pair * 16 + (lane & 15);
      int c  = q * 32 + (lane >> 4) * 8 + e;
      const float* w = (br == 0) ? w2 : ((br == 1) ? w3 : w4);
      int bo = (br + 1) * 32 + oc;
      float inv = bns[bo] * rsqrtf(bnv[bo] + BN_EPS);
      wbtr[i] = f2bf(w[(oc * 128 + c) * 9 + tap] * inv);
    }
  }
}

// ---------------- prep_convf (fallback) ----------------
__global__ void prep_convf_kernel(const float* __restrict__ w2, const float* __restrict__ w3,
                                  const float* __restrict__ w4,
                                  const float* __restrict__ bns, const float* __restrict__ bnv,
                                  float* __restrict__ w24t) {
  int tid = blockIdx.x * blockDim.x + threadIdx.x;
  int nt  = gridDim.x * blockDim.x;
  for (int i = tid; i < 110592; i += nt) {
    int br  = i / 36864;
    int rem = i - br * 36864;
    int c   = rem / 288;
    int k   = (rem % 288) >> 5;
    int o   = rem & 31;
    const float* w = (br == 0) ? w2 : ((br == 1) ? w3 : w4);
    int bo = (br + 1) * 32 + o;
    float inv = bns[bo] * rsqrtf(bnv[bo] + BN_EPS);
    w24t[i] = w[(o * 128 + c) * 9 + k] * inv;
  }
}

// ---------------- a0 (fallback helper — unused on mfma path) ----------------
__global__ __launch_bounds__(256) void a1_kernel(const float* __restrict__ x,
                                                 const float* __restrict__ w1f,
                                                 const float* __restrict__ wkt,
                                                 const float* __restrict__ bfp,
                                                 const float* __restrict__ bk,
                                                 float* __restrict__ out,
                                                 float* __restrict__ Kbuf) {
  __shared__ float lw1[128 * 32];
  __shared__ float lwk[128 * 16];
  __shared__ float lbf[32];
  int t = threadIdx.x;
  for (int i = t; i < 4096; i += 256) lw1[i] = w1f[i];
  for (int i = t; i < 2048; i += 256) lwk[i] = wkt[i];
  if (t < 32) lbf[t] = bfp[t];
  __syncthreads();

  int b  = blockIdx.y;
  int px = blockIdx.x * 256 + t;
  const float* xb = x + (size_t)b * 128 * NPIX;

  float acc[48];
#pragma unroll
  for (int i = 0; i < 48; ++i) acc[i] = 0.f;

  for (int c = 0; c < 128; ++c) {
    float xv = xb[(size_t)c * NPIX + px];
    const float4* w1p = (const float4*)(lw1 + c * 32);
#pragma unroll
    for (int j = 0; j < 8; ++j) {
      float4 w = w1p[j];
      acc[j*4+0] = fmaf(w.x, xv, acc[j*4+0]);
      acc[j*4+1] = fmaf(w.y, xv, acc[j*4+1]);
      acc[j*4+2] = fmaf(w.z, xv, acc[j*4+2]);
      acc[j*4+3] = fmaf(w.w, xv, acc[j*4+3]);
    }
    const float4* wkp = (const float4*)(lwk + c * 16);
#pragma unroll
    for (int j = 0; j < 4; ++j) {
      float4 w = wkp[j];
      acc[32+j*4+0] = fmaf(w.x, xv, acc[32+j*4+0]);
      acc[32+j*4+1] = fmaf(w.y, xv, acc[32+j*4+1]);
      acc[32+j*4+2] = fmaf(w.z, xv, acc[32+j*4+2]);
      acc[32+j*4+3] = fmaf(w.w, xv, acc[32+j*4+3]);
    }
  }
#pragma unroll
  for (int o = 0; o < 32; ++o)
    out[((size_t)(b * 128 + o)) * NPIX + px] = fmaxf(acc[o] + lbf[o], 0.f);
#pragma unroll
  for (int m = 0; m < 16; ++m)
    Kbuf[((size_t)(b * 16 + m)) * NPIX + px] = acc[32 + m] + bk[m];
}

// ---------------- ac: merged a2m (blocks 0..1535, r11 body) + cm (blocks 1536..2559) ----------------
__global__ __launch_bounds__(256) void ac_kernel(const unsigned short* __restrict__ xt,
                                                 const unsigned short* __restrict__ zrow,
                                                 const unsigned short* __restrict__ wbtr,
                                                 const unsigned short* __restrict__ wvbr,
                                                 const unsigned short* __restrict__ wxbr,
                                                 const float* __restrict__ bv,
                                                 const float* __restrict__ bfp,
                                                 const float* __restrict__ bk,
                                                 float* __restrict__ out,
                                                 float* __restrict__ part1,
                                                 float* __restrict__ part2) {
  __shared__ __align__(16) char smem[49168];
  int t = threadIdx.x;
  int wave = t >> 6, lane = t & 63;
  int l15  = lane & 15, cg = lane >> 4;

  if (blockIdx.x < 1536) {
    // ================= a2m (round-11 body) =================
    unsigned short* sx = (unsigned short*)smem;   // 3x16KB + 16B zero page @byte 49152
    int idx  = blockIdx.x;
    int b    = idx & 7;                           // batch -> XCD
    int rest = idx >> 3;
    int h2   = rest & 63;
    int br   = rest >> 6;
    int d    = 6 * (br + 1);
    int h0   = h2 * 2;
    int j    = wave >> 1;
    int whalf = wave & 1;
    int p0   = whalf * 64;

    if (t == 0) *(uint4*)(sx + 24576) = make_uint4(0u, 0u, 0u, 0u);

    const unsigned short* wb    = wbtr + (size_t)br * 36864;
    const unsigned short* slabs = xt + (size_t)b * 4 * 524288;

    f32x4 acc[2][4];
#pragma unroll
    for (int i = 0; i < 2; ++i)
#pragma unroll
      for (int n = 0; n < 4; ++n) acc[i][n] = (f32x4){0.f, 0.f, 0.f, 0.f};

    int pxb[3], xorv[3];
#pragma unroll
    for (int kw = 0; kw < 3; ++kw) {
      pxb[kw]  = p0 + l15 + (kw - 1) * d;
      xorv[kw] = (cg ^ ((pxb[kw] >> 1) & 3)) << 4;
    }

    auto STAGE = [&](int s) {
      int q = s / 3, kh = s % 3;
      int srow = h0 + j + (kh - 1) * d;
      const unsigned short* rowsrc =
          ((unsigned)srow < 128u) ? (slabs + (size_t)q * 524288 + (size_t)srow * 4096)
                                  : zrow;
      const unsigned short* gsrc = rowsrc + whalf * 2048 + lane * 8;
      unsigned short* lbase = sx + (s % 3) * 8192 + j * 4096 + whalf * 2048;
#pragma unroll
      for (int k = 0; k < 4; ++k)
        __builtin_amdgcn_global_load_lds((gas_ptr)(const void*)(gsrc + k * 512),
                                         (las_ptr)(void*)(lbase + k * 512), 16, 0, 0);
    };

    auto COMPUTE = [&](int s) {
      int q = s / 3, kh = s % 3;
      int bb = (s % 3) * 16384 + j * 8192;
      bf16x8 a[3][2];
#pragma unroll
      for (int kw = 0; kw < 3; ++kw) {
        int tap = kh * 3 + kw;
        const unsigned short* wt = wb + ((((size_t)tap * 4 + q) * 2) << 9);
        a[kw][0] = *(const bf16x8*)(wt + lane * 8);
        a[kw][1] = *(const bf16x8*)(wt + 512 + lane * 8);
      }
#pragma unroll
      for (int kw = 0; kw < 3; ++kw) {
        int base = bb + pxb[kw] * 64 + xorv[kw];
#pragma unroll
        for (int nf = 0; nf < 4; ++nf) {
          int px   = pxb[kw] + nf * 16;
          int addr = ((unsigned)px < 128u) ? (base + nf * 1024) : 49152;
          bf16x8 bvv = *(const bf16x8*)((const char*)sx + addr);
          acc[0][nf] = __builtin_amdgcn_mfma_f32_16x16x32_bf16(a[kw][0], bvv, acc[0][nf], 0, 0, 0);
          acc[1][nf] = __builtin_amdgcn_mfma_f32_16x16x32_bf16(a[kw][1], bvv, acc[1][nf], 0, 0, 0);
        }
      }
    };

    STAGE(0);
    STAGE(1);
    __syncthreads();
    for (int s = 0; s < 12; ++s) {
      COMPUTE(s);
      if (s < 10) STAGE(s + 2);
      if (s < 11) {
        if (s < 10) asm volatile("s_waitcnt vmcnt(4)" ::: "memory");
        else        asm volatile("s_waitcnt vmcnt(0)" ::: "memory");
        __builtin_amdgcn_s_barrier();
        __builtin_amdgcn_sched_barrier(0);
      }
    }

    int ocb = (br + 1) * 32;
    int pxw = (h0 + j) * 128 + p0;
#pragma unroll
    for (int mf = 0; mf < 2; ++mf) {
#pragma unroll
      for (int r = 0; r < 4; ++r) {
        int oc = mf * 16 + cg * 4 + r;
        float bias = bfp[ocb + oc];
        float* op = out + ((size_t)(b * 128 + ocb + oc)) * NPIX + pxw + l15;
#pragma unroll
        for (int nf = 0; nf < 4; ++nf)
          op[nf * 16] = fmaxf(acc[mf][nf][r] + bias, 0.f);
      }
    }
  } else {
    // ================= cm (v7 body) =================
    unsigned short* Vl  = (unsigned short*)smem;            // 128*136 bf16 = 34816 B
    unsigned short* knl = (unsigned short*)(smem + 34816);  // 16*136 bf16 = 4352 B
    int idx2 = blockIdx.x - 1536;
    int b    = idx2 & 7;          // batch -> XCD (1024 % 8 == 0)
    int blk  = idx2 >> 3;         // 0..127 == tile
    int ocb  = wave * 32;
    int pbase = blk << 7;
    int cgsw = (cg ^ ((l15 >> 1) & 3)) << 3;

    float bvr[2][4];
#pragma unroll
    for (int mf = 0; mf < 2; ++mf)
#pragma unroll
      for (int r = 0; r < 4; ++r) bvr[mf][r] = bv[ocb + mf * 16 + cg * 4 + r];

    float xb4[4];
#pragma unroll
    for (int r = 0; r < 4; ++r) xb4[r] = 0.f;
    if (wave == 0) {
#pragma unroll
      for (int r = 0; r < 4; ++r) xb4[r] = bfp[cg * 4 + r];
    } else if (wave == 1) {
#pragma unroll
      for (int r = 0; r < 4; ++r) xb4[r] = bfp[16 + cg * 4 + r];
    } else if (wave == 2) {
#pragma unroll
      for (int r = 0; r < 4; ++r) xb4[r] = bk[cg * 4 + r];
    }
    int xwave = (wave < 3) ? wave : 0;

    float kr[4] = {0.f, 0.f, 0.f, 0.f};
    float sv[2][4];
#pragma unroll
    for (int mf = 0; mf < 2; ++mf)
#pragma unroll
      for (int r = 0; r < 4; ++r) sv[mf][r] = 0.f;
    f32x4 am[2];
    am[0] = (f32x4){0.f,0.f,0.f,0.f};
    am[1] = (f32x4){0.f,0.f,0.f,0.f};

#pragma unroll
    for (int hf = 0; hf < 2; ++hf) {
      f32x4 vacc[2][4];
      f32x4 xacc[4];
#pragma unroll
      for (int i = 0; i < 2; ++i)
#pragma unroll
        for (int n = 0; n < 4; ++n) vacc[i][n] = (f32x4){0.f,0.f,0.f,0.f};
#pragma unroll
      for (int n = 0; n < 4; ++n) xacc[n] = (f32x4){0.f,0.f,0.f,0.f};

#pragma unroll
      for (int cc = 0; cc < 4; ++cc) {
        const unsigned short* xq = xt + ((size_t)(b * 4 + cc) * 16384 + pbase) * 32;
        bf16x8 a0 = *(const bf16x8*)(wvbr + ((cc * 8 + wave * 2 + 0) << 9) + lane * 8);
        bf16x8 a1 = *(const bf16x8*)(wvbr + ((cc * 8 + wave * 2 + 1) << 9) + lane * 8);
        bf16x8 ax = *(const bf16x8*)(wxbr + ((cc * 3 + xwave) << 9) + lane * 8);
#pragma unroll
        for (int nf = 0; nf < 4; ++nf) {
          int nfg = hf * 4 + nf;
          bf16x8 bx = *(const bf16x8*)(xq + (size_t)(nfg * 16 + l15) * 32 + cgsw);
          vacc[0][nf] = __builtin_amdgcn_mfma_f32_16x16x32_bf16(a0, bx, vacc[0][nf], 0, 0, 0);
          vacc[1][nf] = __builtin_amdgcn_mfma_f32_16x16x32_bf16(a1, bx, vacc[1][nf], 0, 0, 0);
          if (wave < 3)
            xacc[nf] = __builtin_amdgcn_mfma_f32_16x16x32_bf16(ax, bx, xacc[nf], 0, 0, 0);
        }
      }

#pragma unroll
      for (int mf = 0; mf < 2; ++mf) {
#pragma unroll
        for (int r = 0; r < 4; ++r) {
          float s = 0.f;
#pragma unroll
          for (int nf = 0; nf < 4; ++nf) s += vacc[mf][nf][r];
          sv[mf][r] += s;
          int c = ocb + mf * 16 + cg * 4 + r;
#pragma unroll
          for (int nf = 0; nf < 4; ++nf)
            Vl[c * 136 + (hf * 4 + nf) * 16 + l15] = f2bf(vacc[mf][nf][r] + bvr[mf][r]);
        }
      }

      if (wave < 2) {
#pragma unroll
        for (int r = 0; r < 4; ++r) {
          int oc = wave * 16 + cg * 4 + r;
          float* op = out + ((size_t)(b * 128 + oc)) * NPIX + pbase + l15;
#pragma unroll
          for (int nf = 0; nf < 4; ++nf)
            op[(hf * 4 + nf) * 16] = fmaxf(xacc[nf][r] + xb4[r], 0.f);
        }
      } else if (wave == 2) {
#pragma unroll
        for (int nf = 0; nf < 4; ++nf) {
          int nfg = hf * 4 + nf;
          float kq[4]; float s2 = 0.f;
#pragma unroll
          for (int r = 0; r < 4; ++r) {
            kq[r] = xacc[nf][r] + xb4[r];
            s2 = fmaf(kq[r], kq[r], s2);
          }
          s2 += __shfl_xor(s2, 16);
          s2 += __shfl_xor(s2, 32);
          float inv = rsqrtf(s2);
#pragma unroll
          for (int r = 0; r < 4; ++r) {
            float kn = kq[r] * inv;
            knl[(cg * 4 + r) * 136 + nfg * 16 + l15] = f2bf(kn);
            kr[r] += kn;
          }
        }
      }
    }
    __syncthreads();

#pragma unroll
    for (int ks = 0; ks < 4; ++ks) {
      bf16x8 af = *(const bf16x8*)(knl + l15 * 136 + ks * 32 + cg * 8);
      bf16x8 b0 = *(const bf16x8*)(Vl + (size_t)(ocb + l15) * 136 + ks * 32 + cg * 8);
      bf16x8 b1 = *(const bf16x8*)(Vl + (size_t)(ocb + 16 + l15) * 136 + ks * 32 + cg * 8);
      am[0] = __builtin_amdgcn_mfma_f32_16x16x32_bf16(af, b0, am[0], 0, 0, 0);
      am[1] = __builtin_amdgcn_mfma_f32_16x16x32_bf16(af, b1, am[1], 0, 0, 0);
    }

    float* pp = (blk < 64) ? (part1 + ((size_t)b * 64 + blk) * 2192)
                           : (part2 + ((size_t)b * 64 + (blk - 64)) * 2192);
#pragma unroll
    for (int nf2 = 0; nf2 < 2; ++nf2)
#pragma unroll
      for (int r = 0; r < 4; ++r)
        pp[(cg * 4 + r) * 128 + ocb + nf2 * 16 + l15] = am[nf2][r];
#pragma unroll
    for (int off = 1; off < 16; off <<= 1) {
#pragma unroll
      for (int mf = 0; mf < 2; ++mf)
#pragma unroll
        for (int r = 0; r < 4; ++r)
          sv[mf][r] += __shfl_xor(sv[mf][r], off);
    }
    if (l15 == 0) {
#pragma unroll
      for (int mf = 0; mf < 2; ++mf)
#pragma unroll
        for (int r = 0; r < 4; ++r) {
          int c = ocb + mf * 16 + cg * 4 + r;
          pp[2048 + c] = sv[mf][r] + 128.f * bv[c];
        }
    }
    if (wave == 2) {
#pragma unroll
      for (int off = 1; off < 16; off <<= 1) {
#pragma unroll
        for (int r = 0; r < 4; ++r)
          kr[r] += __shfl_xor(kr[r], off);
      }
      if (l15 == 0) {
#pragma unroll
        for (int r = 0; r < 4; ++r)
          pp[2048 + 128 + cg * 4 + r] = kr[r];
      }
    }
  }
}

// ---------------- a2f (fallback) ----------------
__global__ __launch_bounds__(256) void a2f_kernel(const float* __restrict__ x,
                                                  const float* __restrict__ w24t,
                                                  const float* __restrict__ bfp,
                                                  float* __restrict__ out) {
  int t  = threadIdx.x;
  int og = t & 3;
  int pg = (t >> 2) & 15;
  int r  = t >> 6;
  int br = blockIdx.z;
  int b  = blockIdx.y;
  int h  = blockIdx.x * 4 + r;
  int d  = 6 * (br + 1);

  const float* wt = w24t + (size_t)br * 36864;
  const float* bf = bfp + (br + 1) * 32;
  const float* xb = x + (size_t)b * 128 * NPIX;
  int w0 = pg << 3;

  float acc[8][8];
#pragma unroll
  for (int p = 0; p < 8; ++p)
#pragma unroll
    for (int o = 0; o < 8; ++o) acc[p][o] = 0.f;

  for (int c = 0; c < 128; ++c) {
    const float* xc = xb + (size_t)c * NPIX;
    const float* wc = wt + c * 288;
#pragma unroll
    for (int kh = 0; kh < 3; ++kh) {
      int row = h + (kh - 1) * d;
      if ((unsigned)row >= 128u) continue;
      const float* xr = xc + row * 128;
#pragma unroll
      for (int kw = 0; kw < 3; ++kw) {
        int wb = w0 + (kw - 1) * d;
        float xv[8];
        if (wb >= 0 && wb <= 120) {
          const float2* p2 = (const float2*)(xr + wb);
#pragma unroll
          for (int jj = 0; jj < 4; ++jj) {
            float2 v = p2[jj];
            xv[2*jj] = v.x; xv[2*jj+1] = v.y;
          }
        } else {
#pragma unroll
          for (int jj = 0; jj < 8; ++jj) {
            int ww = wb + jj;
            xv[jj] = ((unsigned)ww < 128u) ? xr[ww] : 0.f;
          }
        }
        const float4* wp = (const float4*)(wc + (kh * 3 + kw) * 32 + og * 8);
        float4 wa = wp[0], wbv = wp[1];
        float wr[8] = {wa.x, wa.y, wa.z, wa.w, wbv.x, wbv.y, wbv.z, wbv.w};
#pragma unroll
        for (int p = 0; p < 8; ++p)
#pragma unroll
          for (int o = 0; o < 8; ++o)
            acc[p][o] = fmaf(xv[p], wr[o], acc[p][o]);
      }
    }
  }

  int chbase = (br + 1) * 32 + og * 8;
  int n = h * 128 + w0;
#pragma unroll
  for (int o = 0; o < 8; ++o) {
    float bias = bf[og * 8 + o];
    float* op = out + ((size_t)(b * 128 + chbase + o)) * NPIX + n;
    float4 v0 = make_float4(fmaxf(acc[0][o] + bias, 0.f), fmaxf(acc[1][o] + bias, 0.f),
                            fmaxf(acc[2][o] + bias, 0.f), fmaxf(acc[3][o] + bias, 0.f));
    float4 v1 = make_float4(fmaxf(acc[4][o] + bias, 0.f), fmaxf(acc[5][o] + bias, 0.f),
                            fmaxf(acc[6][o] + bias, 0.f), fmaxf(acc[7][o] + bias, 0.f));
    ((float4*)op)[0] = v0;
    ((float4*)op)[1] = v1;
  }
}

// ---------------- cf (fallback) ----------------
__global__ __launch_bounds__(256) void cf_kernel(const float* __restrict__ x,
                                                 const float* __restrict__ bv,
                                                 const float* __restrict__ Kbuf,
                                                 const float* __restrict__ wvt,
                                                 float* __restrict__ part) {
  __shared__ float Vl[128 * 129];
  __shared__ float knl[16 * 132];
  int t   = threadIdx.x;
  int b   = blockIdx.y;
  int blk = blockIdx.x;
  const float* Kb = Kbuf + (size_t)b * 16 * NPIX;
  const float* xb = x + (size_t)b * 128 * NPIX;

  int m_own = t & 15;
  int c0    = (t >> 4) << 3;
  int pxg   = t & 15;

  float bvr[8];
#pragma unroll
  for (int jj = 0; jj < 8; ++jj) bvr[jj] = bv[c0 + jj];

  float macc[8] = {0,0,0,0,0,0,0,0};
  float vs[8]   = {0,0,0,0,0,0,0,0};
  float ksum[16];
#pragma unroll
  for (int m = 0; m < 16; ++m) ksum[m] = 0.f;

  for (int tile = blk; tile < 128; tile += 64) {
    __syncthreads();
    int pbase = tile << 7;

    if (t < 128) {
      float kv[16]; float ss = 0.f;
#pragma unroll
      for (int m = 0; m < 16; ++m) {
        kv[m] = Kb[(size_t)m * NPIX + pbase + t];
        ss = fmaf(kv[m], kv[m], ss);
      }
      float inv = rsqrtf(ss);
#pragma unroll
      for (int m = 0; m < 16; ++m) {
        float kn = kv[m] * inv;
        knl[m * 132 + t] = kn;
        ksum[m] += kn;
      }
    }

    float v[8][8];
#pragma unroll
    for (int i = 0; i < 8; ++i)
#pragma unroll
      for (int jj = 0; jj < 8; ++jj) v[i][jj] = 0.f;
    int px0 = pbase + (pxg << 3);
    for (int k = 0; k < 128; ++k) {
      const float4* xp = (const float4*)(xb + (size_t)k * NPIX + px0);
      float4 xa = xp[0], xc4 = xp[1];
      const float4* wp = (const float4*)(wvt + k * 128 + c0);
      float4 wa = wp[0], wc4 = wp[1];
      float xv[8] = {xa.x, xa.y, xa.z, xa.w, xc4.x, xc4.y, xc4.z, xc4.w};
      float wr[8] = {wa.x, wa.y, wa.z, wa.w, wc4.x, wc4.y, wc4.z, wc4.w};
#pragma unroll
      for (int i = 0; i < 8; ++i)
#pragma unroll
        for (int jj = 0; jj < 8; ++jj)
          v[i][jj] = fmaf(wr[i], xv[jj], v[i][jj]);
    }
#pragma unroll
    for (int i = 0; i < 8; ++i)
#pragma unroll
      for (int jj = 0; jj < 8; ++jj)
        Vl[(c0 + i) * 129 + (pxg << 3) + jj] = v[i][jj] + bvr[i];
    __syncthreads();

    for (int px = 0; px < 128; ++px) {
      float knv = knl[m_own * 132 + px];
      float vv[8];
#pragma unroll
      for (int jj = 0; jj < 8; ++jj) vv[jj] = Vl[(c0 + jj) * 129 + px];
#pragma unroll
      for (int jj = 0; jj < 8; ++jj) macc[jj] = fmaf(knv, vv[jj], macc[jj]);
      if (m_own == 0) {
#pragma unroll
        for (int jj = 0; jj < 8; ++jj) vs[jj] += vv[jj];
      }
    }
  }

  int blkid = b * 64 + blk;
  float* pp = part + (size_t)blkid * 2192;
#pragma unroll
  for (int jj = 0; jj < 8; ++jj) pp[m_own * 128 + c0 + jj] = macc[jj];
  if (m_own == 0) {
#pragma unroll
    for (int jj = 0; jj < 8; ++jj) pp[2048 + c0 + jj] = vs[jj];
  }
  __syncthreads();
  if (t < 128) {
#pragma unroll
    for (int m = 0; m < 16; ++m) knl[m * 132 + t] = ksum[m];
  }
  __syncthreads();
  if (t < 16) {
    float s = 0.f;
    for (int i = 0; i < 128; ++i) s += knl[t * 132 + i];
    pp[2048 + 128 + t] = s;
  }
}

// ---------------- reduce (fallback: 64 groups) ----------------
__global__ void reduce_kernel(const float* __restrict__ part, float* __restrict__ stats) {
  int b = blockIdx.y, t = threadIdx.x;
  int e = blockIdx.x * 256 + t;
  if (e >= 2192) return;
  const float* pp = part + (size_t)b * 64 * 2192;
  float s = 0.f;
  for (int g = 0; g < 64; ++g) s += pp[(size_t)g * 2192 + e];
  stats[(size_t)b * 2192 + e] = s;
}

// ---------------- reduce2 (mfma: 64 + 64 groups) ----------------
__global__ void reduce2_kernel(const float* __restrict__ part1,
                               const float* __restrict__ part2,
                               float* __restrict__ stats) {
  int b = blockIdx.y, t = threadIdx.x;
  int e = blockIdx.x * 256 + t;
  if (e >= 2192) return;
  const float* p1 = part1 + (size_t)b * 64 * 2192;
  const float* p2 = part2 + (size_t)b * 64 * 2192;
  float s = 0.f;
  for (int g = 0; g < 64; ++g) s += p1[(size_t)g * 2192 + e];
  for (int g = 0; g < 64; ++g) s += p2[(size_t)g * 2192 + e];
  stats[(size_t)b * 2192 + e] = s;
}

// ---------------- df: fused Q + tailor + final output (1 px/thread) ----------------
__global__ __launch_bounds__(256) void df_kernel(const float* __restrict__ stats,
                                                 const float* __restrict__ wq,
                                                 const float* __restrict__ bq,
                                                 const float* __restrict__ gamma,
                                                 float* __restrict__ out) {
  __shared__ float matl[128 * 16];
  __shared__ float wql[128 * 16];
  __shared__ float vsl[128];
  __shared__ float ksl[16];
  int t = threadIdx.x;
  int b = blockIdx.y;
  const float* st = stats + (size_t)b * 2192;
  for (int i = t; i < 2048; i += 256) {
    int m = i >> 7, c = i & 127;
    matl[c * 16 + m] = st[i];
    wql[c * 16 + m]  = wq[m * 128 + c];
  }
  if (t < 128) vsl[t] = st[2048 + t];
  if (t < 16)  ksl[t] = st[2048 + 128 + t] + EPS_V;
  __syncthreads();

  int px = blockIdx.x * 256 + t;
  float* ob = out + (size_t)b * 128 * NPIX;

  float q[16];
#pragma unroll
  for (int m = 0; m < 16; ++m) q[m] = bq[m];
  for (int c = 0; c < 128; ++c) {
    float xv = ob[(size_t)c * NPIX + px];
    const float4* wp = (const float4*)(wql + c * 16);
#pragma unroll
    for (int jj = 0; jj < 4; ++jj) {
      float4 w = wp[jj];
      q[jj*4+0] = fmaf(w.x, xv, q[jj*4+0]);
      q[jj*4+1] = fmaf(w.y, xv, q[jj*4+1]);
      q[jj*4+2] = fmaf(w.z, xv, q[jj*4+2]);
      q[jj*4+3] = fmaf(w.w, xv, q[jj*4+3]);
    }
  }
  float ss = 0.f;
#pragma unroll
  for (int m = 0; m < 16; ++m) ss = fmaf(q[m], q[m], ss);
  float inv = rsqrtf(ss);
#pragma unroll
  for (int m = 0; m < 16; ++m) q[m] *= inv;
  float den = (float)NPIX;
#pragma unroll
  for (int m = 0; m < 16; ++m) den = fmaf(q[m], ksl[m], den);
  float tl = gamma[0] / den;

  for (int c = 0; c < 128; ++c) {
    float s = vsl[c];
    const float4* mp = (const float4*)(matl + c * 16);
#pragma unroll
    for (int jj = 0; jj < 4; ++jj) {
      float4 w = mp[jj];
      s = fmaf(w.x, q[jj*4+0], s);
      s = fmaf(w.y, q[jj*4+1], s);
      s = fmaf(w.z, q[jj*4+2], s);
      s = fmaf(w.w, q[jj*4+3], s);
    }
    ob[(size_t)c * NPIX + px] = tl * s;
  }
}

extern "C" void kernel_launch(void* const* d_in, const int* in_sizes, int n_in,
                              void* d_out, int out_size, void* d_ws, size_t ws_size,
                              hipStream_t stream) {
  (void)in_sizes; (void)n_in; (void)out_size;
  const float* x   = (const float*)d_in[0];
  const float* w1  = (const float*)d_in[1];
  const float* w2  = (const float*)d_in[2];
  const float* w3  = (const float*)d_in[3];
  const float* w4  = (const float*)d_in[4];
  const float* bns = (const float*)d_in[5];
  const float* bnb = (const float*)d_in[6];
  const float* bnm = (const float*)d_in[7];
  const float* bnv = (const float*)d_in[8];
  const float* wq  = (const float*)d_in[9];
  const float* bq  = (const float*)d_in[10];
  const float* wk  = (const float*)d_in[11];
  const float* bk  = (const float*)d_in[12];
  const float* wv  = (const float*)d_in[13];
  const float* bv  = (const float*)d_in[14];
  const float* gm  = (const float*)d_in[15];
  float* ws  = (float*)d_ws;
  float* out = (float*)d_out;

  float* Kbuf = ws + OFF_K;
  float* w1f  = ws + OFF_W1F;
  float* wkt  = ws + OFF_WKT;
  float* wvt  = ws + OFF_WVT;
  float* bfp  = ws + OFF_BF;
  float* part = ws + OFF_PART;
  float* stat = ws + OFF_STATS;

  bool use_mfma = ws_size >= NEW_END * sizeof(float);
  if (use_mfma) {
    unsigned short* wbtr = (unsigned short*)(ws + OFF_WBT);
    unsigned short* xt   = (unsigned short*)(ws + OFF_XT);
    unsigned short* wvbr = (unsigned short*)(ws + OFF_WVB);
    unsigned short* zrow = (unsigned short*)(ws + OFF_ZROW);
    unsigned short* wxbr = (unsigned short*)(ws + OFF_K);   // first 6144 floats of K region
    float* part2 = ws + OFF_PART2;                          // K region tail (dead in mfma path)
    pa0_kernel<<<dim3(2112), 256, 0, stream>>>(x, xt, w1, w2, w3, w4,
                                               bns, bnb, bnm, bnv, wk, wv,
                                               wbtr, wvbr, wxbr, zrow, bfp);
    ac_kernel<<<dim3(2560), 256, 0, stream>>>(xt, zrow, wbtr, wvbr, wxbr,
                                              bv, bfp, bk, out, part, part2);
    reduce2_kernel<<<dim3(9, 8), 256, 0, stream>>>(part, part2, stat);
    df_kernel<<<dim3(64, 8), 256, 0, stream>>>(stat, wq, bq, gm, out);
  } else {
    float* w24t = ws + OFF_W24T;
    prep_common_kernel<<<64, 256, 0, stream>>>(w1, bns, bnb, bnm, bnv, wk, wv,
                                               w1f, wkt, wvt, bfp);
    prep_convf_kernel<<<64, 256, 0, stream>>>(w2, w3, w4, bns, bnv, w24t);
    a1_kernel<<<dim3(64, 8), 256, 0, stream>>>(x, w1f, wkt, bfp, bk, out, Kbuf);
    a2f_kernel<<<dim3(32, 8, 3), 256, 0, stream>>>(x, w24t, bfp, out);
    cf_kernel<<<dim3(64, 8), 256, 0, stream>>>(x, bv, Kbuf, wvt, part);
    reduce_kernel<<<dim3(9, 8), 256, 0, stream>>>(part, stat);
    df_kernel<<<dim3(64, 8), 256, 0, stream>>>(stat, wq, bq, gm, out);
  }
}

// Round 14
// 138.237 us; speedup vs baseline: 1.0319x; 1.0319x over previous
//
#include <hip/hip_runtime.h>
#include <hip/hip_bf16.h>
#include <math.h>

#define NPIX   16384
#define BATCH  8
#define BN_EPS 1e-5f
#define EPS_V  1e-6f

typedef __attribute__((ext_vector_type(8))) short bf16x8;
typedef __attribute__((ext_vector_type(4))) float f32x4;
typedef const __attribute__((address_space(1))) unsigned int* gas_ptr;
typedef __attribute__((address_space(3))) unsigned int* las_ptr;

// ---- workspace layout (float offsets) ----
#define OFF_K     ((size_t)0)          // fallback: Kbuf. mfma path: wxbr + part2
#define OFF_PART2 ((size_t)8192)       // mfma: 512*2192 = 1122304 (ends 1130496 < 2097152)
#define OFF_W1F   ((size_t)2097152)    // 128*32   = 4096
#define OFF_WKT   ((size_t)2101248)    // 128*16   = 2048
#define OFF_WVT   ((size_t)2103296)    // 128*128  = 16384
#define OFF_BF    ((size_t)2119680)    // 4*32     = 128
#define OFF_PART  ((size_t)2119808)    // 512*2192 = 1122304
#define OFF_STATS ((size_t)3242112)    // 8*2192   = 17536
#define BASE_END  ((size_t)3259648)
// mfma path extras
#define OFF_WBT   BASE_END             // 3*9*4*2*64*8 ushort = 55296 floats
#define OFF_XT    ((size_t)3314976)    // 8*4*16384*32 ushort = 8388608 floats (PRE-SWIZZLED)
#define OFF_WVB   ((size_t)11703584)   // 4*8*64*8 ushort = 8192 floats
#define OFF_ZROW  ((size_t)11711776)   // 4096 ushort zero row = 2048 floats
#define NEW_END   ((size_t)11713824)
// fallback extras
#define OFF_W24T  BASE_END             // 3*128*9*32 = 110592

__device__ inline unsigned short f2bf(float f) {
  union { float f; unsigned int u; } v; v.f = f;
  unsigned int r = (v.u + 0x7FFFu + ((v.u >> 16) & 1u)) >> 16;
  return (unsigned short)r;
}

// ---------------- prep_common (fallback path only) ----------------
__global__ void prep_common_kernel(const float* __restrict__ w1,
                                   const float* __restrict__ bns, const float* __restrict__ bnb,
                                   const float* __restrict__ bnm, const float* __restrict__ bnv,
                                   const float* __restrict__ wk, const float* __restrict__ wv,
                                   float* __restrict__ w1f, float* __restrict__ wkt,
                                   float* __restrict__ wvt, float* __restrict__ bf) {
  int tid = blockIdx.x * blockDim.x + threadIdx.x;
  int nt  = gridDim.x * blockDim.x;
  for (int i = tid; i < 128; i += nt) {
    float inv = bns[i] * rsqrtf(bnv[i] + BN_EPS);
    bf[i] = bnb[i] - bnm[i] * inv;
  }
  for (int i = tid; i < 4096; i += nt) {          // w1f[c][o]
    int c = i >> 5, o = i & 31;
    float inv = bns[o] * rsqrtf(bnv[o] + BN_EPS);
    w1f[i] = w1[o * 128 + c] * inv;
  }
  for (int i = tid; i < 2048; i += nt) {          // wkt[c][m]
    int c = i >> 4, m = i & 15;
    wkt[i] = wk[m * 128 + c];
  }
  for (int i = tid; i < 16384; i += nt) {         // wvt[c][o]
    int c = i >> 7, o = i & 127;
    wvt[i] = wv[o * 128 + c];
  }
}

// ---------------- pa0: merged a0 (blocks 0..2047) + prep_convb (blocks 2048..2111) ----------------
__global__ __launch_bounds__(256) void pa0_kernel(const float* __restrict__ x,
                                                  unsigned short* __restrict__ xt,
                                                  const float* __restrict__ w1,
                                                  const float* __restrict__ w2,
                                                  const float* __restrict__ w3,
                                                  const float* __restrict__ w4,
                                                  const float* __restrict__ bns,
                                                  const float* __restrict__ bnb,
                                                  const float* __restrict__ bnm,
                                                  const float* __restrict__ bnv,
                                                  const float* __restrict__ wk,
                                                  const float* __restrict__ wv,
                                                  unsigned short* __restrict__ wbtr,
                                                  unsigned short* __restrict__ wvbr,
                                                  unsigned short* __restrict__ wxbr,
                                                  unsigned short* __restrict__ zrow,
                                                  float* __restrict__ bf) {
  __shared__ unsigned short Ts[64][132];
  int t   = threadIdx.x;
  int idx = blockIdx.x;
  if (idx < 2048) {
    // ---- a0: transpose x -> xt bf16, quarter-major, pre-swizzled 16B units ----
    int b   = idx & 7;
    int px0 = (idx >> 3) * 64;
    const float* xb = x + (size_t)b * 128 * NPIX;
    int p = t & 63, cq = t >> 6;
#pragma unroll 8
    for (int i = 0; i < 32; ++i) {
      int c = cq * 32 + i;
      Ts[p][c] = f2bf(xb[(size_t)c * NPIX + px0 + p]);
    }
    __syncthreads();
    int pw = t >> 2, cg = t & 3;
    unsigned short* dst = xt + ((size_t)(b * 4 + cg) * 16384 + px0 + pw) * 32;
    int sw = (pw >> 1) & 3;
#pragma unroll
    for (int k = 0; k < 8; ++k) {
      uint2 v = *(const uint2*)(&Ts[pw][cg * 32 + k * 4]);
      int cgs = (k >> 1) ^ sw;
      *(uint2*)(dst + cgs * 8 + (k & 1) * 4) = v;
    }
  } else {
    // ---- prep_convb (grid-stride over 64 virtual blocks) ----
    int tid = (idx - 2048) * 256 + t;
    int nt  = 64 * 256;
    for (int i = tid; i < 128; i += nt) {
      float inv = bns[i] * rsqrtf(bnv[i] + BN_EPS);
      bf[i] = bnb[i] - bnm[i] * inv;
    }
    for (int i = tid; i < 4096; i += nt) zrow[i] = 0;
    for (int i = tid; i < 16384; i += nt) {
      int e = i & 7, lane = (i >> 3) & 63, f = (i >> 9) & 7, q = i >> 12;
      int oc = f * 16 + (lane & 15);
      int c  = q * 32 + (lane >> 4) * 8 + e;
      wvbr[i] = f2bf(wv[oc * 128 + c]);
    }
    for (int i = tid; i < 6144; i += nt) {
      int e = i & 7, lane = (i >> 3) & 63, ct = i >> 9;
      int tile = ct % 3, q = ct / 3;
      int c = q * 32 + (lane >> 4) * 8 + e;
      float val;
      if (tile < 2) {
        int oc = tile * 16 + (lane & 15);
        val = w1[oc * 128 + c] * (bns[oc] * rsqrtf(bnv[oc] + BN_EPS));
      } else {
        val = wk[(lane & 15) * 128 + c];
      }
      wxbr[i] = f2bf(val);
    }
    for (int i = tid; i < 110592; i += nt) {
      int br = i / 36864;
      int r  = i - br * 36864;
      int tap  = r >> 12;
      int r2   = r & 4095;
      int q    = r2 >> 10;
      int r3   = r2 & 1023;
      int pair = r3 >> 9;
      int r4   = r3 & 511;
      int lane = r4 >> 3, e = r4 & 7;
      int oc = pair * 16 + (lane & 15);
      int c  = q * 32 + (lane >> 4) * 8 + e;
      const float* w = (br == 0) ? w2 : ((br == 1) ? w3 : w4);
      int bo = (br + 1) * 32 + oc;
      float inv = bns[bo] * rsqrtf(bnv[bo] + BN_EPS);
      wbtr[i] = f2bf(w[(oc * 128 + c) * 9 + tap] * inv);
    }
  }
}

// ---------------- prep_convf (fallback) ----------------
__global__ void prep_convf_kernel(const float* __restrict__ w2, const float* __restrict__ w3,
                                  const float* __restrict__ w4,
                                  const float* __restrict__ bns, const float* __restrict__ bnv,
                                  float* __restrict__ w24t) {
  int tid = blockIdx.x * blockDim.x + threadIdx.x;
  int nt  = gridDim.x * blockDim.x;
  for (int i = tid; i < 110592; i += nt) {
    int br  = i / 36864;
    int rem = i - br * 36864;
    int c   = rem / 288;
    int k   = (rem % 288) >> 5;
    int o   = rem & 31;
    const float* w = (br == 0) ? w2 : ((br == 1) ? w3 : w4);
    int bo = (br + 1) * 32 + o;
    float inv = bns[bo] * rsqrtf(bnv[bo] + BN_EPS);
    w24t[i] = w[(o * 128 + c) * 9 + k] * inv;
  }
}

// ---------------- a1 (fallback only) ----------------
__global__ __launch_bounds__(256) void a1_kernel(const float* __restrict__ x,
                                                 const float* __restrict__ w1f,
                                                 const float* __restrict__ wkt,
                                                 const float* __restrict__ bfp,
                                                 const float* __restrict__ bk,
                                                 float* __restrict__ out,
                                                 float* __restrict__ Kbuf) {
  __shared__ float lw1[128 * 32];
  __shared__ float lwk[128 * 16];
  __shared__ float lbf[32];
  int t = threadIdx.x;
  for (int i = t; i < 4096; i += 256) lw1[i] = w1f[i];
  for (int i = t; i < 2048; i += 256) lwk[i] = wkt[i];
  if (t < 32) lbf[t] = bfp[t];
  __syncthreads();

  int b  = blockIdx.y;
  int px = blockIdx.x * 256 + t;
  const float* xb = x + (size_t)b * 128 * NPIX;

  float acc[48];
#pragma unroll
  for (int i = 0; i < 48; ++i) acc[i] = 0.f;

  for (int c = 0; c < 128; ++c) {
    float xv = xb[(size_t)c * NPIX + px];
    const float4* w1p = (const float4*)(lw1 + c * 32);
#pragma unroll
    for (int j = 0; j < 8; ++j) {
      float4 w = w1p[j];
      acc[j*4+0] = fmaf(w.x, xv, acc[j*4+0]);
      acc[j*4+1] = fmaf(w.y, xv, acc[j*4+1]);
      acc[j*4+2] = fmaf(w.z, xv, acc[j*4+2]);
      acc[j*4+3] = fmaf(w.w, xv, acc[j*4+3]);
    }
    const float4* wkp = (const float4*)(lwk + c * 16);
#pragma unroll
    for (int j = 0; j < 4; ++j) {
      float4 w = wkp[j];
      acc[32+j*4+0] = fmaf(w.x, xv, acc[32+j*4+0]);
      acc[32+j*4+1] = fmaf(w.y, xv, acc[32+j*4+1]);
      acc[32+j*4+2] = fmaf(w.z, xv, acc[32+j*4+2]);
      acc[32+j*4+3] = fmaf(w.w, xv, acc[32+j*4+3]);
    }
  }
#pragma unroll
  for (int o = 0; o < 32; ++o)
    out[((size_t)(b * 128 + o)) * NPIX + px] = fmaxf(acc[o] + lbf[o], 0.f);
#pragma unroll
  for (int m = 0; m < 16; ++m)
    Kbuf[((size_t)(b * 16 + m)) * NPIX + px] = acc[32 + m] + bk[m];
}

// ---------------- ac v2: 3:2 interleaved a2m/cm, batch->XCD preserved, 39168B LDS ----------------
__global__ __launch_bounds__(256) void ac_kernel(const unsigned short* __restrict__ xt,
                                                 const unsigned short* __restrict__ zrow,
                                                 const unsigned short* __restrict__ wbtr,
                                                 const unsigned short* __restrict__ wvbr,
                                                 const unsigned short* __restrict__ wxbr,
                                                 const float* __restrict__ bv,
                                                 const float* __restrict__ bfp,
                                                 const float* __restrict__ bk,
                                                 float* __restrict__ out,
                                                 float* __restrict__ part1,
                                                 float* __restrict__ part2) {
  __shared__ __align__(16) char smem[39168];
  int t = threadIdx.x;
  int wave = t >> 6, lane = t & 63;
  int l15  = lane & 15, cg = lane >> 4;

  int idx = blockIdx.x;
  int b   = idx & 7;                 // batch -> XCD (preserved by remap)
  int u   = idx >> 3;                // 0..319
  int r5  = u % 5, g = u / 5;        // 3:2 interleave

  if (r5 < 3) {
    // ================= a2m: 2x16KB buffers + LDS zero page @32768, 1-deep pipeline ===========
    unsigned short* sx = (unsigned short*)smem;
    int rest = g * 3 + r5;           // 0..191
    int h2   = rest & 63;
    int br   = rest >> 6;
    int d    = 6 * (br + 1);
    int h0   = h2 * 2;
    int j    = wave >> 1;
    int whalf = wave & 1;
    int p0   = whalf * 64;

    if (t == 0) *(uint4*)(smem + 32768) = make_uint4(0u, 0u, 0u, 0u);

    const unsigned short* wb    = wbtr + (size_t)br * 36864;
    const unsigned short* slabs = xt + (size_t)b * 4 * 524288;

    f32x4 acc[2][4];
#pragma unroll
    for (int i = 0; i < 2; ++i)
#pragma unroll
      for (int n = 0; n < 4; ++n) acc[i][n] = (f32x4){0.f, 0.f, 0.f, 0.f};

    int pxb[3], xorv[3];
#pragma unroll
    for (int kw = 0; kw < 3; ++kw) {
      pxb[kw]  = p0 + l15 + (kw - 1) * d;
      xorv[kw] = (cg ^ ((pxb[kw] >> 1) & 3)) << 4;
    }

    auto STAGE = [&](int s) {
      int q = s / 3, kh = s % 3;
      int srow = h0 + j + (kh - 1) * d;
      const unsigned short* rowsrc =
          ((unsigned)srow < 128u) ? (slabs + (size_t)q * 524288 + (size_t)srow * 4096)
                                  : zrow;
      const unsigned short* gsrc = rowsrc + whalf * 2048 + lane * 8;
      unsigned short* lbase = sx + (s & 1) * 8192 + j * 4096 + whalf * 2048;
#pragma unroll
      for (int k = 0; k < 4; ++k)
        __builtin_amdgcn_global_load_lds((gas_ptr)(const void*)(gsrc + k * 512),
                                         (las_ptr)(void*)(lbase + k * 512), 16, 0, 0);
    };

    auto COMPUTE = [&](int s) {
      int q = s / 3, kh = s % 3;
      int bb = (s & 1) * 16384 + j * 8192;
      bf16x8 a[3][2];
#pragma unroll
      for (int kw = 0; kw < 3; ++kw) {
        int tap = kh * 3 + kw;
        const unsigned short* wt = wb + ((((size_t)tap * 4 + q) * 2) << 9);
        a[kw][0] = *(const bf16x8*)(wt + lane * 8);
        a[kw][1] = *(const bf16x8*)(wt + 512 + lane * 8);
      }
#pragma unroll
      for (int kw = 0; kw < 3; ++kw) {
        int base = bb + pxb[kw] * 64 + xorv[kw];
#pragma unroll
        for (int nf = 0; nf < 4; ++nf) {
          int px   = pxb[kw] + nf * 16;
          int addr = ((unsigned)px < 128u) ? (base + nf * 1024) : 32768;
          bf16x8 bvv = *(const bf16x8*)((const char*)sx + addr);
          acc[0][nf] = __builtin_amdgcn_mfma_f32_16x16x32_bf16(a[kw][0], bvv, acc[0][nf], 0, 0, 0);
          acc[1][nf] = __builtin_amdgcn_mfma_f32_16x16x32_bf16(a[kw][1], bvv, acc[1][nf], 0, 0, 0);
        }
      }
    };

    STAGE(0);
    asm volatile("s_waitcnt vmcnt(0)" ::: "memory");
    __builtin_amdgcn_s_barrier();
    __builtin_amdgcn_sched_barrier(0);
    for (int s = 0; s < 12; ++s) {
      if (s < 11) STAGE(s + 1);
      COMPUTE(s);
      if (s < 11) {
        asm volatile("s_waitcnt vmcnt(0)" ::: "memory");
        __builtin_amdgcn_s_barrier();
        __builtin_amdgcn_sched_barrier(0);
      }
    }

    int ocb = (br + 1) * 32;
    int pxw = (h0 + j) * 128 + p0;
#pragma unroll
    for (int mf = 0; mf < 2; ++mf) {
#pragma unroll
      for (int r = 0; r < 4; ++r) {
        int oc = mf * 16 + cg * 4 + r;
        float bias = bfp[ocb + oc];
        float* op = out + ((size_t)(b * 128 + ocb + oc)) * NPIX + pxw + l15;
#pragma unroll
        for (int nf = 0; nf < 4; ++nf)
          op[nf * 16] = fmaxf(acc[mf][nf][r] + bias, 0.f);
      }
    }
  } else {
    // ================= cm (v7 body) =================
    unsigned short* Vl  = (unsigned short*)smem;            // 128*136 bf16 = 34816 B
    unsigned short* knl = (unsigned short*)(smem + 34816);  // 16*136 bf16 = 4352 B
    int blk  = g * 2 + (r5 - 3);     // 0..127 == tile
    int ocb  = wave * 32;
    int pbase = blk << 7;
    int cgsw = (cg ^ ((l15 >> 1) & 3)) << 3;

    float bvr[2][4];
#pragma unroll
    for (int mf = 0; mf < 2; ++mf)
#pragma unroll
      for (int r = 0; r < 4; ++r) bvr[mf][r] = bv[ocb + mf * 16 + cg * 4 + r];

    float xb4[4];
#pragma unroll
    for (int r = 0; r < 4; ++r) xb4[r] = 0.f;
    if (wave == 0) {
#pragma unroll
      for (int r = 0; r < 4; ++r) xb4[r] = bfp[cg * 4 + r];
    } else if (wave == 1) {
#pragma unroll
      for (int r = 0; r < 4; ++r) xb4[r] = bfp[16 + cg * 4 + r];
    } else if (wave == 2) {
#pragma unroll
      for (int r = 0; r < 4; ++r) xb4[r] = bk[cg * 4 + r];
    }
    int xwave = (wave < 3) ? wave : 0;

    float kr[4] = {0.f, 0.f, 0.f, 0.f};
    float sv[2][4];
#pragma unroll
    for (int mf = 0; mf < 2; ++mf)
#pragma unroll
      for (int r = 0; r < 4; ++r) sv[mf][r] = 0.f;
    f32x4 am[2];
    am[0] = (f32x4){0.f,0.f,0.f,0.f};
    am[1] = (f32x4){0.f,0.f,0.f,0.f};

#pragma unroll
    for (int hf = 0; hf < 2; ++hf) {
      f32x4 vacc[2][4];
      f32x4 xacc[4];
#pragma unroll
      for (int i = 0; i < 2; ++i)
#pragma unroll
        for (int n = 0; n < 4; ++n) vacc[i][n] = (f32x4){0.f,0.f,0.f,0.f};
#pragma unroll
      for (int n = 0; n < 4; ++n) xacc[n] = (f32x4){0.f,0.f,0.f,0.f};

#pragma unroll
      for (int cc = 0; cc < 4; ++cc) {
        const unsigned short* xq = xt + ((size_t)(b * 4 + cc) * 16384 + pbase) * 32;
        bf16x8 a0 = *(const bf16x8*)(wvbr + ((cc * 8 + wave * 2 + 0) << 9) + lane * 8);
        bf16x8 a1 = *(const bf16x8*)(wvbr + ((cc * 8 + wave * 2 + 1) << 9) + lane * 8);
        bf16x8 ax = *(const bf16x8*)(wxbr + ((cc * 3 + xwave) << 9) + lane * 8);
#pragma unroll
        for (int nf = 0; nf < 4; ++nf) {
          int nfg = hf * 4 + nf;
          bf16x8 bx = *(const bf16x8*)(xq + (size_t)(nfg * 16 + l15) * 32 + cgsw);
          vacc[0][nf] = __builtin_amdgcn_mfma_f32_16x16x32_bf16(a0, bx, vacc[0][nf], 0, 0, 0);
          vacc[1][nf] = __builtin_amdgcn_mfma_f32_16x16x32_bf16(a1, bx, vacc[1][nf], 0, 0, 0);
          if (wave < 3)
            xacc[nf] = __builtin_amdgcn_mfma_f32_16x16x32_bf16(ax, bx, xacc[nf], 0, 0, 0);
        }
      }

#pragma unroll
      for (int mf = 0; mf < 2; ++mf) {
#pragma unroll
        for (int r = 0; r < 4; ++r) {
          float s = 0.f;
#pragma unroll
          for (int nf = 0; nf < 4; ++nf) s += vacc[mf][nf][r];
          sv[mf][r] += s;
          int c = ocb + mf * 16 + cg * 4 + r;
#pragma unroll
          for (int nf = 0; nf < 4; ++nf)
            Vl[c * 136 + (hf * 4 + nf) * 16 + l15] = f2bf(vacc[mf][nf][r] + bvr[mf][r]);
        }
      }

      if (wave < 2) {
#pragma unroll
        for (int r = 0; r < 4; ++r) {
          int oc = wave * 16 + cg * 4 + r;
          float* op = out + ((size_t)(b * 128 + oc)) * NPIX + pbase + l15;
#pragma unroll
          for (int nf = 0; nf < 4; ++nf)
            op[(hf * 4 + nf) * 16] = fmaxf(xacc[nf][r] + xb4[r], 0.f);
        }
      } else if (wave == 2) {
#pragma unroll
        for (int nf = 0; nf < 4; ++nf) {
          int nfg = hf * 4 + nf;
          float kq[4]; float s2 = 0.f;
#pragma unroll
          for (int r = 0; r < 4; ++r) {
            kq[r] = xacc[nf][r] + xb4[r];
            s2 = fmaf(kq[r], kq[r], s2);
          }
          s2 += __shfl_xor(s2, 16);
          s2 += __shfl_xor(s2, 32);
          float inv = rsqrtf(s2);
#pragma unroll
          for (int r = 0; r < 4; ++r) {
            float kn = kq[r] * inv;
            knl[(cg * 4 + r) * 136 + nfg * 16 + l15] = f2bf(kn);
            kr[r] += kn;
          }
        }
      }
    }
    __syncthreads();

#pragma unroll
    for (int ks = 0; ks < 4; ++ks) {
      bf16x8 af = *(const bf16x8*)(knl + l15 * 136 + ks * 32 + cg * 8);
      bf16x8 b0 = *(const bf16x8*)(Vl + (size_t)(ocb + l15) * 136 + ks * 32 + cg * 8);
      bf16x8 b1 = *(const bf16x8*)(Vl + (size_t)(ocb + 16 + l15) * 136 + ks * 32 + cg * 8);
      am[0] = __builtin_amdgcn_mfma_f32_16x16x32_bf16(af, b0, am[0], 0, 0, 0);
      am[1] = __builtin_amdgcn_mfma_f32_16x16x32_bf16(af, b1, am[1], 0, 0, 0);
    }

    float* pp = (blk < 64) ? (part1 + ((size_t)b * 64 + blk) * 2192)
                           : (part2 + ((size_t)b * 64 + (blk - 64)) * 2192);
#pragma unroll
    for (int nf2 = 0; nf2 < 2; ++nf2)
#pragma unroll
      for (int r = 0; r < 4; ++r)
        pp[(cg * 4 + r) * 128 + ocb + nf2 * 16 + l15] = am[nf2][r];
#pragma unroll
    for (int off = 1; off < 16; off <<= 1) {
#pragma unroll
      for (int mf = 0; mf < 2; ++mf)
#pragma unroll
        for (int r = 0; r < 4; ++r)
          sv[mf][r] += __shfl_xor(sv[mf][r], off);
    }
    if (l15 == 0) {
#pragma unroll
      for (int mf = 0; mf < 2; ++mf)
#pragma unroll
        for (int r = 0; r < 4; ++r) {
          int c = ocb + mf * 16 + cg * 4 + r;
          pp[2048 + c] = sv[mf][r] + 128.f * bv[c];
        }
    }
    if (wave == 2) {
#pragma unroll
      for (int off = 1; off < 16; off <<= 1) {
#pragma unroll
        for (int r = 0; r < 4; ++r)
          kr[r] += __shfl_xor(kr[r], off);
      }
      if (l15 == 0) {
#pragma unroll
        for (int r = 0; r < 4; ++r)
          pp[2048 + 128 + cg * 4 + r] = kr[r];
      }
    }
  }
}

// ---------------- a2f (fallback) ----------------
__global__ __launch_bounds__(256) void a2f_kernel(const float* __restrict__ x,
                                                  const float* __restrict__ w24t,
                                                  const float* __restrict__ bfp,
                                                  float* __restrict__ out) {
  int t  = threadIdx.x;
  int og = t & 3;
  int pg = (t >> 2) & 15;
  int r  = t >> 6;
  int br = blockIdx.z;
  int b  = blockIdx.y;
  int h  = blockIdx.x * 4 + r;
  int d  = 6 * (br + 1);

  const float* wt = w24t + (size_t)br * 36864;
  const float* bf = bfp + (br + 1) * 32;
  const float* xb = x + (size_t)b * 128 * NPIX;
  int w0 = pg << 3;

  float acc[8][8];
#pragma unroll
  for (int p = 0; p < 8; ++p)
#pragma unroll
    for (int o = 0; o < 8; ++o) acc[p][o] = 0.f;

  for (int c = 0; c < 128; ++c) {
    const float* xc = xb + (size_t)c * NPIX;
    const float* wc = wt + c * 288;
#pragma unroll
    for (int kh = 0; kh < 3; ++kh) {
      int row = h + (kh - 1) * d;
      if ((unsigned)row >= 128u) continue;
      const float* xr = xc + row * 128;
#pragma unroll
      for (int kw = 0; kw < 3; ++kw) {
        int wb = w0 + (kw - 1) * d;
        float xv[8];
        if (wb >= 0 && wb <= 120) {
          const float2* p2 = (const float2*)(xr + wb);
#pragma unroll
          for (int jj = 0; jj < 4; ++jj) {
            float2 v = p2[jj];
            xv[2*jj] = v.x; xv[2*jj+1] = v.y;
          }
        } else {
#pragma unroll
          for (int jj = 0; jj < 8; ++jj) {
            int ww = wb + jj;
            xv[jj] = ((unsigned)ww < 128u) ? xr[ww] : 0.f;
          }
        }
        const float4* wp = (const float4*)(wc + (kh * 3 + kw) * 32 + og * 8);
        float4 wa = wp[0], wbv = wp[1];
        float wr[8] = {wa.x, wa.y, wa.z, wa.w, wbv.x, wbv.y, wbv.z, wbv.w};
#pragma unroll
        for (int p = 0; p < 8; ++p)
#pragma unroll
          for (int o = 0; o < 8; ++o)
            acc[p][o] = fmaf(xv[p], wr[o], acc[p][o]);
      }
    }
  }

  int chbase = (br + 1) * 32 + og * 8;
  int n = h * 128 + w0;
#pragma unroll
  for (int o = 0; o < 8; ++o) {
    float bias = bf[og * 8 + o];
    float* op = out + ((size_t)(b * 128 + chbase + o)) * NPIX + n;
    float4 v0 = make_float4(fmaxf(acc[0][o] + bias, 0.f), fmaxf(acc[1][o] + bias, 0.f),
                            fmaxf(acc[2][o] + bias, 0.f), fmaxf(acc[3][o] + bias, 0.f));
    float4 v1 = make_float4(fmaxf(acc[4][o] + bias, 0.f), fmaxf(acc[5][o] + bias, 0.f),
                            fmaxf(acc[6][o] + bias, 0.f), fmaxf(acc[7][o] + bias, 0.f));
    ((float4*)op)[0] = v0;
    ((float4*)op)[1] = v1;
  }
}

// ---------------- cf (fallback) ----------------
__global__ __launch_bounds__(256) void cf_kernel(const float* __restrict__ x,
                                                 const float* __restrict__ bv,
                                                 const float* __restrict__ Kbuf,
                                                 const float* __restrict__ wvt,
                                                 float* __restrict__ part) {
  __shared__ float Vl[128 * 129];
  __shared__ float knl[16 * 132];
  int t   = threadIdx.x;
  int b   = blockIdx.y;
  int blk = blockIdx.x;
  const float* Kb = Kbuf + (size_t)b * 16 * NPIX;
  const float* xb = x + (size_t)b * 128 * NPIX;

  int m_own = t & 15;
  int c0    = (t >> 4) << 3;
  int pxg   = t & 15;

  float bvr[8];
#pragma unroll
  for (int jj = 0; jj < 8; ++jj) bvr[jj] = bv[c0 + jj];

  float macc[8] = {0,0,0,0,0,0,0,0};
  float vs[8]   = {0,0,0,0,0,0,0,0};
  float ksum[16];
#pragma unroll
  for (int m = 0; m < 16; ++m) ksum[m] = 0.f;

  for (int tile = blk; tile < 128; tile += 64) {
    __syncthreads();
    int pbase = tile << 7;

    if (t < 128) {
      float kv[16]; float ss = 0.f;
#pragma unroll
      for (int m = 0; m < 16; ++m) {
        kv[m] = Kb[(size_t)m * NPIX + pbase + t];
        ss = fmaf(kv[m], kv[m], ss);
      }
      float inv = rsqrtf(ss);
#pragma unroll
      for (int m = 0; m < 16; ++m) {
        float kn = kv[m] * inv;
        knl[m * 132 + t] = kn;
        ksum[m] += kn;
      }
    }

    float v[8][8];
#pragma unroll
    for (int i = 0; i < 8; ++i)
#pragma unroll
      for (int jj = 0; jj < 8; ++jj) v[i][jj] = 0.f;
    int px0 = pbase + (pxg << 3);
    for (int k = 0; k < 128; ++k) {
      const float4* xp = (const float4*)(xb + (size_t)k * NPIX + px0);
      float4 xa = xp[0], xc4 = xp[1];
      const float4* wp = (const float4*)(wvt + k * 128 + c0);
      float4 wa = wp[0], wc4 = wp[1];
      float xv[8] = {xa.x, xa.y, xa.z, xa.w, xc4.x, xc4.y, xc4.z, xc4.w};
      float wr[8] = {wa.x, wa.y, wa.z, wa.w, wc4.x, wc4.y, wc4.z, wc4.w};
#pragma unroll
      for (int i = 0; i < 8; ++i)
#pragma unroll
        for (int jj = 0; jj < 8; ++jj)
          v[i][jj] = fmaf(wr[i], xv[jj], v[i][jj]);
    }
#pragma unroll
    for (int i = 0; i < 8; ++i)
#pragma unroll
      for (int jj = 0; jj < 8; ++jj)
        Vl[(c0 + i) * 129 + (pxg << 3) + jj] = v[i][jj] + bvr[i];
    __syncthreads();

    for (int px = 0; px < 128; ++px) {
      float knv = knl[m_own * 132 + px];
      float vv[8];
#pragma unroll
      for (int jj = 0; jj < 8; ++jj) vv[jj] = Vl[(c0 + jj) * 129 + px];
#pragma unroll
      for (int jj = 0; jj < 8; ++jj) macc[jj] = fmaf(knv, vv[jj], macc[jj]);
      if (m_own == 0) {
#pragma unroll
        for (int jj = 0; jj < 8; ++jj) vs[jj] += vv[jj];
      }
    }
  }

  int blkid = b * 64 + blk;
  float* pp = part + (size_t)blkid * 2192;
#pragma unroll
  for (int jj = 0; jj < 8; ++jj) pp[m_own * 128 + c0 + jj] = macc[jj];
  if (m_own == 0) {
#pragma unroll
    for (int jj = 0; jj < 8; ++jj) pp[2048 + c0 + jj] = vs[jj];
  }
  __syncthreads();
  if (t < 128) {
#pragma unroll
    for (int m = 0; m < 16; ++m) knl[m * 132 + t] = ksum[m];
  }
  __syncthreads();
  if (t < 16) {
    float s = 0.f;
    for (int i = 0; i < 128; ++i) s += knl[t * 132 + i];
    pp[2048 + 128 + t] = s;
  }
}

// ---------------- reduce (fallback: 64 groups) ----------------
__global__ void reduce_kernel(const float* __restrict__ part, float* __restrict__ stats) {
  int b = blockIdx.y, t = threadIdx.x;
  int e = blockIdx.x * 256 + t;
  if (e >= 2192) return;
  const float* pp = part + (size_t)b * 64 * 2192;
  float s = 0.f;
  for (int g = 0; g < 64; ++g) s += pp[(size_t)g * 2192 + e];
  stats[(size_t)b * 2192 + e] = s;
}

// ---------------- reduce2 (mfma: 64 + 64 groups) ----------------
__global__ void reduce2_kernel(const float* __restrict__ part1,
                               const float* __restrict__ part2,
                               float* __restrict__ stats) {
  int b = blockIdx.y, t = threadIdx.x;
  int e = blockIdx.x * 256 + t;
  if (e >= 2192) return;
  const float* p1 = part1 + (size_t)b * 64 * 2192;
  const float* p2 = part2 + (size_t)b * 64 * 2192;
  float s = 0.f;
  for (int g = 0; g < 64; ++g) s += p1[(size_t)g * 2192 + e];
  for (int g = 0; g < 64; ++g) s += p2[(size_t)g * 2192 + e];
  stats[(size_t)b * 2192 + e] = s;
}

// ---------------- df: fused Q + tailor + final output (1 px/thread) ----------------
__global__ __launch_bounds__(256) void df_kernel(const float* __restrict__ stats,
                                                 const float* __restrict__ wq,
                                                 const float* __restrict__ bq,
                                                 const float* __restrict__ gamma,
                                                 float* __restrict__ out) {
  __shared__ float matl[128 * 16];
  __shared__ float wql[128 * 16];
  __shared__ float vsl[128];
  __shared__ float ksl[16];
  int t = threadIdx.x;
  int b = blockIdx.y;
  const float* st = stats + (size_t)b * 2192;
  for (int i = t; i < 2048; i += 256) {
    int m = i >> 7, c = i & 127;
    matl[c * 16 + m] = st[i];
    wql[c * 16 + m]  = wq[m * 128 + c];
  }
  if (t < 128) vsl[t] = st[2048 + t];
  if (t < 16)  ksl[t] = st[2048 + 128 + t] + EPS_V;
  __syncthreads();

  int px = blockIdx.x * 256 + t;
  float* ob = out + (size_t)b * 128 * NPIX;

  float q[16];
#pragma unroll
  for (int m = 0; m < 16; ++m) q[m] = bq[m];
  for (int c = 0; c < 128; ++c) {
    float xv = ob[(size_t)c * NPIX + px];
    const float4* wp = (const float4*)(wql + c * 16);
#pragma unroll
    for (int jj = 0; jj < 4; ++jj) {
      float4 w = wp[jj];
      q[jj*4+0] = fmaf(w.x, xv, q[jj*4+0]);
      q[jj*4+1] = fmaf(w.y, xv, q[jj*4+1]);
      q[jj*4+2] = fmaf(w.z, xv, q[jj*4+2]);
      q[jj*4+3] = fmaf(w.w, xv, q[jj*4+3]);
    }
  }
  float ss = 0.f;
#pragma unroll
  for (int m = 0; m < 16; ++m) ss = fmaf(q[m], q[m], ss);
  float inv = rsqrtf(ss);
#pragma unroll
  for (int m = 0; m < 16; ++m) q[m] *= inv;
  float den = (float)NPIX;
#pragma unroll
  for (int m = 0; m < 16; ++m) den = fmaf(q[m], ksl[m], den);
  float tl = gamma[0] / den;

  for (int c = 0; c < 128; ++c) {
    float s = vsl[c];
    const float4* mp = (const float4*)(matl + c * 16);
#pragma unroll
    for (int jj = 0; jj < 4; ++jj) {
      float4 w = mp[jj];
      s = fmaf(w.x, q[jj*4+0], s);
      s = fmaf(w.y, q[jj*4+1], s);
      s = fmaf(w.z, q[jj*4+2], s);
      s = fmaf(w.w, q[jj*4+3], s);
    }
    ob[(size_t)c * NPIX + px] = tl * s;
  }
}

extern "C" void kernel_launch(void* const* d_in, const int* in_sizes, int n_in,
                              void* d_out, int out_size, void* d_ws, size_t ws_size,
                              hipStream_t stream) {
  (void)in_sizes; (void)n_in; (void)out_size;
  const float* x   = (const float*)d_in[0];
  const float* w1  = (const float*)d_in[1];
  const float* w2  = (const float*)d_in[2];
  const float* w3  = (const float*)d_in[3];
  const float* w4  = (const float*)d_in[4];
  const float* bns = (const float*)d_in[5];
  const float* bnb = (const float*)d_in[6];
  const float* bnm = (const float*)d_in[7];
  const float* bnv = (const float*)d_in[8];
  const float* wq  = (const float*)d_in[9];
  const float* bq  = (const float*)d_in[10];
  const float* wk  = (const float*)d_in[11];
  const float* bk  = (const float*)d_in[12];
  const float* wv  = (const float*)d_in[13];
  const float* bv  = (const float*)d_in[14];
  const float* gm  = (const float*)d_in[15];
  float* ws  = (float*)d_ws;
  float* out = (float*)d_out;

  float* Kbuf = ws + OFF_K;
  float* w1f  = ws + OFF_W1F;
  float* wkt  = ws + OFF_WKT;
  float* wvt  = ws + OFF_WVT;
  float* bfp  = ws + OFF_BF;
  float* part = ws + OFF_PART;
  float* stat = ws + OFF_STATS;

  bool use_mfma = ws_size >= NEW_END * sizeof(float);
  if (use_mfma) {
    unsigned short* wbtr = (unsigned short*)(ws + OFF_WBT);
    unsigned short* xt   = (unsigned short*)(ws + OFF_XT);
    unsigned short* wvbr = (unsigned short*)(ws + OFF_WVB);
    unsigned short* zrow = (unsigned short*)(ws + OFF_ZROW);
    unsigned short* wxbr = (unsigned short*)(ws + OFF_K);   // first 6144 floats of K region
    float* part2 = ws + OFF_PART2;                          // K region tail (dead in mfma path)
    pa0_kernel<<<dim3(2112), 256, 0, stream>>>(x, xt, w1, w2, w3, w4,
                                               bns, bnb, bnm, bnv, wk, wv,
                                               wbtr, wvbr, wxbr, zrow, bfp);
    ac_kernel<<<dim3(2560), 256, 0, stream>>>(xt, zrow, wbtr, wvbr, wxbr,
                                              bv, bfp, bk, out, part, part2);
    reduce2_kernel<<<dim3(9, 8), 256, 0, stream>>>(part, part2, stat);
    df_kernel<<<dim3(64, 8), 256, 0, stream>>>(stat, wq, bq, gm, out);
  } else {
    float* w24t = ws + OFF_W24T;
    prep_common_kernel<<<64, 256, 0, stream>>>(w1, bns, bnb, bnm, bnv, wk, wv,
                                               w1f, wkt, wvt, bfp);
    prep_convf_kernel<<<64, 256, 0, stream>>>(w2, w3, w4, bns, bnv, w24t);
    a1_kernel<<<dim3(64, 8), 256, 0, stream>>>(x, w1f, wkt, bfp, bk, out, Kbuf);
    a2f_kernel<<<dim3(32, 8, 3), 256, 0, stream>>>(x, w24t, bfp, out);
    cf_kernel<<<dim3(64, 8), 256, 0, stream>>>(x, bv, Kbuf, wvt, part);
    reduce_kernel<<<dim3(9, 8), 256, 0, stream>>>(part, stat);
    df_kernel<<<dim3(64, 8), 256, 0, stream>>>(stat, wq, bq, gm, out);
  }
}

// Round 15
// 130.825 us; speedup vs baseline: 1.0904x; 1.0567x over previous
//
#include <hip/hip_runtime.h>
#include <hip/hip_bf16.h>
#include <math.h>

#define NPIX   16384
#define BATCH  8
#define BN_EPS 1e-5f
#define EPS_V  1e-6f

typedef __attribute__((ext_vector_type(8))) short bf16x8;
typedef __attribute__((ext_vector_type(4))) float f32x4;
typedef const __attribute__((address_space(1))) unsigned int* gas_ptr;
typedef __attribute__((address_space(3))) unsigned int* las_ptr;

// ---- workspace layout (float offsets) ----
#define OFF_K     ((size_t)0)          // fallback: Kbuf. mfma path: wxbr + part2
#define OFF_PART2 ((size_t)8192)       // mfma: 512*2192 = 1122304 (ends 1130496 < 2097152)
#define OFF_W1F   ((size_t)2097152)    // 128*32   = 4096
#define OFF_WKT   ((size_t)2101248)    // 128*16   = 2048
#define OFF_WVT   ((size_t)2103296)    // 128*128  = 16384
#define OFF_BF    ((size_t)2119680)    // 4*32     = 128
#define OFF_PART  ((size_t)2119808)    // 512*2192 = 1122304
#define OFF_STATS ((size_t)3242112)    // 8*2192   = 17536
#define BASE_END  ((size_t)3259648)
// mfma path extras
#define OFF_WBT   BASE_END             // 3*9*4*2*64*8 ushort = 55296 floats
#define OFF_XT    ((size_t)3314976)    // 8*4*16384*32 ushort = 8388608 floats (PRE-SWIZZLED)
#define OFF_WVB   ((size_t)11703584)   // 4*8*64*8 ushort = 8192 floats
#define OFF_ZROW  ((size_t)11711776)   // 4096 ushort zero row = 2048 floats
#define NEW_END   ((size_t)11713824)
// fallback extras
#define OFF_W24T  BASE_END             // 3*128*9*32 = 110592

__device__ inline unsigned short f2bf(float f) {
  union { float f; unsigned int u; } v; v.f = f;
  unsigned int r = (v.u + 0x7FFFu + ((v.u >> 16) & 1u)) >> 16;
  return (unsigned short)r;
}

// ---------------- prep_common (fallback path only) ----------------
__global__ void prep_common_kernel(const float* __restrict__ w1,
                                   const float* __restrict__ bns, const float* __restrict__ bnb,
                                   const float* __restrict__ bnm, const float* __restrict__ bnv,
                                   const float* __restrict__ wk, const float* __restrict__ wv,
                                   float* __restrict__ w1f, float* __restrict__ wkt,
                                   float* __restrict__ wvt, float* __restrict__ bf) {
  int tid = blockIdx.x * blockDim.x + threadIdx.x;
  int nt  = gridDim.x * blockDim.x;
  for (int i = tid; i < 128; i += nt) {
    float inv = bns[i] * rsqrtf(bnv[i] + BN_EPS);
    bf[i] = bnb[i] - bnm[i] * inv;
  }
  for (int i = tid; i < 4096; i += nt) {          // w1f[c][o]
    int c = i >> 5, o = i & 31;
    float inv = bns[o] * rsqrtf(bnv[o] + BN_EPS);
    w1f[i] = w1[o * 128 + c] * inv;
  }
  for (int i = tid; i < 2048; i += nt) {          // wkt[c][m]
    int c = i >> 4, m = i & 15;
    wkt[i] = wk[m * 128 + c];
  }
  for (int i = tid; i < 16384; i += nt) {         // wvt[c][o]
    int c = i >> 7, o = i & 127;
    wvt[i] = wv[o * 128 + c];
  }
}

// ---------------- pa0: merged a0 (blocks 0..2047) + prep_convb (blocks 2048..2111) ----------------
__global__ __launch_bounds__(256) void pa0_kernel(const float* __restrict__ x,
                                                  unsigned short* __restrict__ xt,
                                                  const float* __restrict__ w1,
                                                  const float* __restrict__ w2,
                                                  const float* __restrict__ w3,
                                                  const float* __restrict__ w4,
                                                  const float* __restrict__ bns,
                                                  const float* __restrict__ bnb,
                                                  const float* __restrict__ bnm,
                                                  const float* __restrict__ bnv,
                                                  const float* __restrict__ wk,
                                                  const float* __restrict__ wv,
                                                  unsigned short* __restrict__ wbtr,
                                                  unsigned short* __restrict__ wvbr,
                                                  unsigned short* __restrict__ wxbr,
                                                  unsigned short* __restrict__ zrow,
                                                  float* __restrict__ bf) {
  __shared__ unsigned short Ts[64][132];
  int t   = threadIdx.x;
  int idx = blockIdx.x;
  if (idx < 2048) {
    // ---- a0: transpose x -> xt bf16, quarter-major, pre-swizzled 16B units ----
    int b   = idx & 7;
    int px0 = (idx >> 3) * 64;
    const float* xb = x + (size_t)b * 128 * NPIX;
    int p = t & 63, cq = t >> 6;
#pragma unroll 8
    for (int i = 0; i < 32; ++i) {
      int c = cq * 32 + i;
      Ts[p][c] = f2bf(xb[(size_t)c * NPIX + px0 + p]);
    }
    __syncthreads();
    int pw = t >> 2, cg = t & 3;
    unsigned short* dst = xt + ((size_t)(b * 4 + cg) * 16384 + px0 + pw) * 32;
    int sw = (pw >> 1) & 3;
#pragma unroll
    for (int k = 0; k < 8; ++k) {
      uint2 v = *(const uint2*)(&Ts[pw][cg * 32 + k * 4]);
      int cgs = (k >> 1) ^ sw;
      *(uint2*)(dst + cgs * 8 + (k & 1) * 4) = v;
    }
  } else {
    // ---- prep_convb (grid-stride over 64 virtual blocks) ----
    int tid = (idx - 2048) * 256 + t;
    int nt  = 64 * 256;
    for (int i = tid; i < 128; i += nt) {
      float inv = bns[i] * rsqrtf(bnv[i] + BN_EPS);
      bf[i] = bnb[i] - bnm[i] * inv;
    }
    for (int i = tid; i < 4096; i += nt) zrow[i] = 0;
    for (int i = tid; i < 16384; i += nt) {
      int e = i & 7, lane = (i >> 3) & 63, f = (i >> 9) & 7, q = i >> 12;
      int oc = f * 16 + (lane & 15);
      int c  = q * 32 + (lane >> 4) * 8 + e;
      wvbr[i] = f2bf(wv[oc * 128 + c]);
    }
    for (int i = tid; i < 6144; i += nt) {
      int e = i & 7, lane = (i >> 3) & 63, ct = i >> 9;
      int tile = ct % 3, q = ct / 3;
      int c = q * 32 + (lane >> 4) * 8 + e;
      float val;
      if (tile < 2) {
        int oc = tile * 16 + (lane & 15);
        val = w1[oc * 128 + c] * (bns[oc] * rsqrtf(bnv[oc] + BN_EPS));
      } else {
        val = wk[(lane & 15) * 128 + c];
      }
      wxbr[i] = f2bf(val);
    }
    for (int i = tid; i < 110592; i += nt) {
      int br = i / 36864;
      int r  = i - br * 36864;
      int tap  = r >> 12;
      int r2   = r & 4095;
      int q    = r2 >> 10;
      int r3   = r2 & 1023;
      int pair = r3 >> 9;
      int r4   = r3 & 511;
      int lane = r4 >> 3, e = r4 & 7;
      int oc = pair * 16 + (lane & 15);
      int c  = q * 32 + (lane >> 4) * 8 + e;
      const float* w = (br == 0) ? w2 : ((br == 1) ? w3 : w4);
      int bo = (br + 1) * 32 + oc;
      float inv = bns[bo] * rsqrtf(bnv[bo] + BN_EPS);
      wbtr[i] = f2bf(w[(oc * 128 + c) * 9 + tap] * inv);
    }
  }
}

// ---------------- prep_convf (fallback) ----------------
__global__ void prep_convf_kernel(const float* __restrict__ w2, const float* __restrict__ w3,
                                  const float* __restrict__ w4,
                                  const float* __restrict__ bns, const float* __restrict__ bnv,
                                  float* __restrict__ w24t) {
  int tid = blockIdx.x * blockDim.x + threadIdx.x;
  int nt  = gridDim.x * blockDim.x;
  for (int i = tid; i < 110592; i += nt) {
    int br  = i / 36864;
    int rem = i - br * 36864;
    int c   = rem / 288;
    int k   = (rem % 288) >> 5;
    int o   = rem & 31;
    const float* w = (br == 0) ? w2 : ((br == 1) ? w3 : w4);
    int bo = (br + 1) * 32 + o;
    float inv = bns[bo] * rsqrtf(bnv[bo] + BN_EPS);
    w24t[i] = w[(o * 128 + c) * 9 + k] * inv;
  }
}

// ---------------- a1 (fallback only) ----------------
__global__ __launch_bounds__(256) void a1_kernel(const float* __restrict__ x,
                                                 const float* __restrict__ w1f,
                                                 const float* __restrict__ wkt,
                                                 const float* __restrict__ bfp,
                                                 const float* __restrict__ bk,
                                                 float* __restrict__ out,
                                                 float* __restrict__ Kbuf) {
  __shared__ float lw1[128 * 32];
  __shared__ float lwk[128 * 16];
  __shared__ float lbf[32];
  int t = threadIdx.x;
  for (int i = t; i < 4096; i += 256) lw1[i] = w1f[i];
  for (int i = t; i < 2048; i += 256) lwk[i] = wkt[i];
  if (t < 32) lbf[t] = bfp[t];
  __syncthreads();

  int b  = blockIdx.y;
  int px = blockIdx.x * 256 + t;
  const float* xb = x + (size_t)b * 128 * NPIX;

  float acc[48];
#pragma unroll
  for (int i = 0; i < 48; ++i) acc[i] = 0.f;

  for (int c = 0; c < 128; ++c) {
    float xv = xb[(size_t)c * NPIX + px];
    const float4* w1p = (const float4*)(lw1 + c * 32);
#pragma unroll
    for (int j = 0; j < 8; ++j) {
      float4 w = w1p[j];
      acc[j*4+0] = fmaf(w.x, xv, acc[j*4+0]);
      acc[j*4+1] = fmaf(w.y, xv, acc[j*4+1]);
      acc[j*4+2] = fmaf(w.z, xv, acc[j*4+2]);
      acc[j*4+3] = fmaf(w.w, xv, acc[j*4+3]);
    }
    const float4* wkp = (const float4*)(lwk + c * 16);
#pragma unroll
    for (int j = 0; j < 4; ++j) {
      float4 w = wkp[j];
      acc[32+j*4+0] = fmaf(w.x, xv, acc[32+j*4+0]);
      acc[32+j*4+1] = fmaf(w.y, xv, acc[32+j*4+1]);
      acc[32+j*4+2] = fmaf(w.z, xv, acc[32+j*4+2]);
      acc[32+j*4+3] = fmaf(w.w, xv, acc[32+j*4+3]);
    }
  }
#pragma unroll
  for (int o = 0; o < 32; ++o)
    out[((size_t)(b * 128 + o)) * NPIX + px] = fmaxf(acc[o] + lbf[o], 0.f);
#pragma unroll
  for (int m = 0; m < 16; ++m)
    Kbuf[((size_t)(b * 16 + m)) * NPIX + px] = acc[32 + m] + bk[m];
}

// ---------------- a2m (round-11 body): 3x16KB buffers, counted-vmcnt 2-deep pipeline ----------------
__global__ __launch_bounds__(256) void a2m_kernel(const unsigned short* __restrict__ xt,
                                                  const unsigned short* __restrict__ zrow,
                                                  const unsigned short* __restrict__ wbtr,
                                                  const float* __restrict__ bfp,
                                                  float* __restrict__ out) {
  __shared__ unsigned short sx[3 * 8192 + 8];   // 3x16KB sub-buffers + 16B zero page @byte 49152
  int t    = threadIdx.x;
  int wave = t >> 6, lane = t & 63;
  int l15  = lane & 15, cg = lane >> 4;
  int idx  = blockIdx.x;
  int b    = idx & 7;                           // batch -> XCD
  int rest = idx >> 3;
  int h2   = rest & 63;
  int br   = rest >> 6;
  int d    = 6 * (br + 1);
  int h0   = h2 * 2;
  int j    = wave >> 1;                         // row of the pair this wave computes/stages
  int whalf = wave & 1;                         // px half (compute) / row half (stage)
  int p0   = whalf * 64;

  if (t == 0) *(uint4*)(sx + 24576) = make_uint4(0u, 0u, 0u, 0u);

  const unsigned short* wb    = wbtr + (size_t)br * 36864;
  const unsigned short* slabs = xt + (size_t)b * 4 * 524288;

  f32x4 acc[2][4];
#pragma unroll
  for (int i = 0; i < 2; ++i)
#pragma unroll
    for (int n = 0; n < 4; ++n) acc[i][n] = (f32x4){0.f, 0.f, 0.f, 0.f};

  int pxb[3], xorv[3];
#pragma unroll
  for (int kw = 0; kw < 3; ++kw) {
    pxb[kw]  = p0 + l15 + (kw - 1) * d;
    xorv[kw] = (cg ^ ((pxb[kw] >> 1) & 3)) << 4;
  }

  auto STAGE = [&](int s) {
    int q = s / 3, kh = s % 3;
    int srow = h0 + j + (kh - 1) * d;
    const unsigned short* rowsrc =
        ((unsigned)srow < 128u) ? (slabs + (size_t)q * 524288 + (size_t)srow * 4096)
                                : zrow;
    const unsigned short* gsrc = rowsrc + whalf * 2048 + lane * 8;
    unsigned short* lbase = sx + (s % 3) * 8192 + j * 4096 + whalf * 2048;
#pragma unroll
    for (int k = 0; k < 4; ++k)
      __builtin_amdgcn_global_load_lds((gas_ptr)(const void*)(gsrc + k * 512),
                                       (las_ptr)(void*)(lbase + k * 512), 16, 0, 0);
  };

  auto COMPUTE = [&](int s) {
    int q = s / 3, kh = s % 3;
    int bb = (s % 3) * 16384 + j * 8192;        // byte base of this wave's row
    bf16x8 a[3][2];
#pragma unroll
    for (int kw = 0; kw < 3; ++kw) {
      int tap = kh * 3 + kw;
      const unsigned short* wt = wb + ((((size_t)tap * 4 + q) * 2) << 9);
      a[kw][0] = *(const bf16x8*)(wt + lane * 8);
      a[kw][1] = *(const bf16x8*)(wt + 512 + lane * 8);
    }
#pragma unroll
    for (int kw = 0; kw < 3; ++kw) {
      int base = bb + pxb[kw] * 64 + xorv[kw];
#pragma unroll
      for (int nf = 0; nf < 4; ++nf) {
        int px   = pxb[kw] + nf * 16;
        int addr = ((unsigned)px < 128u) ? (base + nf * 1024) : 49152;
        bf16x8 bv = *(const bf16x8*)((const char*)sx + addr);
        acc[0][nf] = __builtin_amdgcn_mfma_f32_16x16x32_bf16(a[kw][0], bv, acc[0][nf], 0, 0, 0);
        acc[1][nf] = __builtin_amdgcn_mfma_f32_16x16x32_bf16(a[kw][1], bv, acc[1][nf], 0, 0, 0);
      }
    }
  };

  STAGE(0);
  STAGE(1);
  __syncthreads();                              // full drain once: buffers 0,1 ready; zero page visible
  for (int s = 0; s < 12; ++s) {
    COMPUTE(s);
    if (s < 10) STAGE(s + 2);                   // keep 2 stages in flight
    if (s < 11) {
      if (s < 10) asm volatile("s_waitcnt vmcnt(4)" ::: "memory");
      else        asm volatile("s_waitcnt vmcnt(0)" ::: "memory");
      __builtin_amdgcn_s_barrier();
      __builtin_amdgcn_sched_barrier(0);
    }
  }

  int ocb = (br + 1) * 32;
  int pxw = (h0 + j) * 128 + p0;
#pragma unroll
  for (int mf = 0; mf < 2; ++mf) {
#pragma unroll
    for (int r = 0; r < 4; ++r) {
      int oc = mf * 16 + cg * 4 + r;
      float bias = bfp[ocb + oc];
      float* op = out + ((size_t)(b * 128 + ocb + oc)) * NPIX + pxw + l15;
#pragma unroll
      for (int nf = 0; nf < 4; ++nf)
        op[nf * 16] = fmaxf(acc[mf][nf][r] + bias, 0.f);
    }
  }
}

// ---------------- a2f (fallback) ----------------
__global__ __launch_bounds__(256) void a2f_kernel(const float* __restrict__ x,
                                                  const float* __restrict__ w24t,
                                                  const float* __restrict__ bfp,
                                                  float* __restrict__ out) {
  int t  = threadIdx.x;
  int og = t & 3;
  int pg = (t >> 2) & 15;
  int r  = t >> 6;
  int br = blockIdx.z;
  int b  = blockIdx.y;
  int h  = blockIdx.x * 4 + r;
  int d  = 6 * (br + 1);

  const float* wt = w24t + (size_t)br * 36864;
  const float* bf = bfp + (br + 1) * 32;
  const float* xb = x + (size_t)b * 128 * NPIX;
  int w0 = pg << 3;

  float acc[8][8];
#pragma unroll
  for (int p = 0; p < 8; ++p)
#pragma unroll
    for (int o = 0; o < 8; ++o) acc[p][o] = 0.f;

  for (int c = 0; c < 128; ++c) {
    const float* xc = xb + (size_t)c * NPIX;
    const float* wc = wt + c * 288;
#pragma unroll
    for (int kh = 0; kh < 3; ++kh) {
      int row = h + (kh - 1) * d;
      if ((unsigned)row >= 128u) continue;
      const float* xr = xc + row * 128;
#pragma unroll
      for (int kw = 0; kw < 3; ++kw) {
        int wb = w0 + (kw - 1) * d;
        float xv[8];
        if (wb >= 0 && wb <= 120) {
          const float2* p2 = (const float2*)(xr + wb);
#pragma unroll
          for (int jj = 0; jj < 4; ++jj) {
            float2 v = p2[jj];
            xv[2*jj] = v.x; xv[2*jj+1] = v.y;
          }
        } else {
#pragma unroll
          for (int jj = 0; jj < 8; ++jj) {
            int ww = wb + jj;
            xv[jj] = ((unsigned)ww < 128u) ? xr[ww] : 0.f;
          }
        }
        const float4* wp = (const float4*)(wc + (kh * 3 + kw) * 32 + og * 8);
        float4 wa = wp[0], wbv = wp[1];
        float wr[8] = {wa.x, wa.y, wa.z, wa.w, wbv.x, wbv.y, wbv.z, wbv.w};
#pragma unroll
        for (int p = 0; p < 8; ++p)
#pragma unroll
          for (int o = 0; o < 8; ++o)
            acc[p][o] = fmaf(xv[p], wr[o], acc[p][o]);
      }
    }
  }

  int chbase = (br + 1) * 32 + og * 8;
  int n = h * 128 + w0;
#pragma unroll
  for (int o = 0; o < 8; ++o) {
    float bias = bf[og * 8 + o];
    float* op = out + ((size_t)(b * 128 + chbase + o)) * NPIX + n;
    float4 v0 = make_float4(fmaxf(acc[0][o] + bias, 0.f), fmaxf(acc[1][o] + bias, 0.f),
                            fmaxf(acc[2][o] + bias, 0.f), fmaxf(acc[3][o] + bias, 0.f));
    float4 v1 = make_float4(fmaxf(acc[4][o] + bias, 0.f), fmaxf(acc[5][o] + bias, 0.f),
                            fmaxf(acc[6][o] + bias, 0.f), fmaxf(acc[7][o] + bias, 0.f));
    ((float4*)op)[0] = v0;
    ((float4*)op)[1] = v1;
  }
}

// ---------------- cm v7: 1 tile/block, batch->XCD swizzle, swizzled-xt reads ----------------
__global__ __launch_bounds__(256) void cm_kernel(const unsigned short* __restrict__ xt,
                                                 const unsigned short* __restrict__ wvbr,
                                                 const unsigned short* __restrict__ wxbr,
                                                 const float* __restrict__ bv,
                                                 const float* __restrict__ bfp,
                                                 const float* __restrict__ bk,
                                                 float* __restrict__ out,
                                                 float* __restrict__ part1,
                                                 float* __restrict__ part2) {
  __shared__ __align__(16) unsigned short Vl[128 * 136];   // bf16 [oc][px]
  __shared__ __align__(16) unsigned short knl[16 * 136];   // bf16 [m][px]
  int t    = threadIdx.x;
  int idx  = blockIdx.x;
  int b    = idx & 7;           // batch -> XCD (1024 % 8 == 0, bijective)
  int blk  = idx >> 3;          // 0..127 == tile
  int wave = t >> 6, lane = t & 63;
  int l15  = lane & 15, cg = lane >> 4;
  int ocb  = wave * 32;
  int pbase = blk << 7;
  int cgsw = (cg ^ ((l15 >> 1) & 3)) << 3;   // swizzled-xt unit offset (ushorts)

  float bvr[2][4];
#pragma unroll
  for (int mf = 0; mf < 2; ++mf)
#pragma unroll
    for (int r = 0; r < 4; ++r) bvr[mf][r] = bv[ocb + mf * 16 + cg * 4 + r];

  float xb4[4];
#pragma unroll
  for (int r = 0; r < 4; ++r) xb4[r] = 0.f;
  if (wave == 0) {
#pragma unroll
    for (int r = 0; r < 4; ++r) xb4[r] = bfp[cg * 4 + r];
  } else if (wave == 1) {
#pragma unroll
    for (int r = 0; r < 4; ++r) xb4[r] = bfp[16 + cg * 4 + r];
  } else if (wave == 2) {
#pragma unroll
    for (int r = 0; r < 4; ++r) xb4[r] = bk[cg * 4 + r];
  }
  int xwave = (wave < 3) ? wave : 0;

  float kr[4] = {0.f, 0.f, 0.f, 0.f};
  float sv[2][4];
#pragma unroll
  for (int mf = 0; mf < 2; ++mf)
#pragma unroll
    for (int r = 0; r < 4; ++r) sv[mf][r] = 0.f;
  f32x4 am[2];
  am[0] = (f32x4){0.f,0.f,0.f,0.f};
  am[1] = (f32x4){0.f,0.f,0.f,0.f};

#pragma unroll
  for (int hf = 0; hf < 2; ++hf) {
    f32x4 vacc[2][4];
    f32x4 xacc[4];
#pragma unroll
    for (int i = 0; i < 2; ++i)
#pragma unroll
      for (int n = 0; n < 4; ++n) vacc[i][n] = (f32x4){0.f,0.f,0.f,0.f};
#pragma unroll
    for (int n = 0; n < 4; ++n) xacc[n] = (f32x4){0.f,0.f,0.f,0.f};

#pragma unroll
    for (int cc = 0; cc < 4; ++cc) {
      const unsigned short* xq = xt + ((size_t)(b * 4 + cc) * 16384 + pbase) * 32;
      bf16x8 a0 = *(const bf16x8*)(wvbr + ((cc * 8 + wave * 2 + 0) << 9) + lane * 8);
      bf16x8 a1 = *(const bf16x8*)(wvbr + ((cc * 8 + wave * 2 + 1) << 9) + lane * 8);
      bf16x8 ax = *(const bf16x8*)(wxbr + ((cc * 3 + xwave) << 9) + lane * 8);
#pragma unroll
      for (int nf = 0; nf < 4; ++nf) {
        int nfg = hf * 4 + nf;
        bf16x8 bx = *(const bf16x8*)(xq + (size_t)(nfg * 16 + l15) * 32 + cgsw);
        vacc[0][nf] = __builtin_amdgcn_mfma_f32_16x16x32_bf16(a0, bx, vacc[0][nf], 0, 0, 0);
        vacc[1][nf] = __builtin_amdgcn_mfma_f32_16x16x32_bf16(a1, bx, vacc[1][nf], 0, 0, 0);
        if (wave < 3)
          xacc[nf] = __builtin_amdgcn_mfma_f32_16x16x32_bf16(ax, bx, xacc[nf], 0, 0, 0);
      }
    }

#pragma unroll
    for (int mf = 0; mf < 2; ++mf) {
#pragma unroll
      for (int r = 0; r < 4; ++r) {
        float s = 0.f;
#pragma unroll
        for (int nf = 0; nf < 4; ++nf) s += vacc[mf][nf][r];
        sv[mf][r] += s;
        int c = ocb + mf * 16 + cg * 4 + r;
#pragma unroll
        for (int nf = 0; nf < 4; ++nf)
          Vl[c * 136 + (hf * 4 + nf) * 16 + l15] = f2bf(vacc[mf][nf][r] + bvr[mf][r]);
      }
    }

    if (wave < 2) {
#pragma unroll
      for (int r = 0; r < 4; ++r) {
        int oc = wave * 16 + cg * 4 + r;
        float* op = out + ((size_t)(b * 128 + oc)) * NPIX + pbase + l15;
#pragma unroll
        for (int nf = 0; nf < 4; ++nf)
          op[(hf * 4 + nf) * 16] = fmaxf(xacc[nf][r] + xb4[r], 0.f);
      }
    } else if (wave == 2) {
#pragma unroll
      for (int nf = 0; nf < 4; ++nf) {
        int nfg = hf * 4 + nf;
        float kq[4]; float s2 = 0.f;
#pragma unroll
        for (int r = 0; r < 4; ++r) {
          kq[r] = xacc[nf][r] + xb4[r];
          s2 = fmaf(kq[r], kq[r], s2);
        }
        s2 += __shfl_xor(s2, 16);
        s2 += __shfl_xor(s2, 32);
        float inv = rsqrtf(s2);
#pragma unroll
        for (int r = 0; r < 4; ++r) {
          float kn = kq[r] * inv;
          knl[(cg * 4 + r) * 136 + nfg * 16 + l15] = f2bf(kn);
          kr[r] += kn;
        }
      }
    }
  }
  __syncthreads();

#pragma unroll
  for (int ks = 0; ks < 4; ++ks) {
    bf16x8 af = *(const bf16x8*)(knl + l15 * 136 + ks * 32 + cg * 8);
    bf16x8 b0 = *(const bf16x8*)(Vl + (size_t)(ocb + l15) * 136 + ks * 32 + cg * 8);
    bf16x8 b1 = *(const bf16x8*)(Vl + (size_t)(ocb + 16 + l15) * 136 + ks * 32 + cg * 8);
    am[0] = __builtin_amdgcn_mfma_f32_16x16x32_bf16(af, b0, am[0], 0, 0, 0);
    am[1] = __builtin_amdgcn_mfma_f32_16x16x32_bf16(af, b1, am[1], 0, 0, 0);
  }

  float* pp = (blk < 64) ? (part1 + ((size_t)b * 64 + blk) * 2192)
                         : (part2 + ((size_t)b * 64 + (blk - 64)) * 2192);
#pragma unroll
  for (int nf2 = 0; nf2 < 2; ++nf2)
#pragma unroll
    for (int r = 0; r < 4; ++r)
      pp[(cg * 4 + r) * 128 + ocb + nf2 * 16 + l15] = am[nf2][r];
#pragma unroll
  for (int off = 1; off < 16; off <<= 1) {
#pragma unroll
    for (int mf = 0; mf < 2; ++mf)
#pragma unroll
      for (int r = 0; r < 4; ++r)
        sv[mf][r] += __shfl_xor(sv[mf][r], off);
  }
  if (l15 == 0) {
#pragma unroll
    for (int mf = 0; mf < 2; ++mf)
#pragma unroll
      for (int r = 0; r < 4; ++r) {
        int c = ocb + mf * 16 + cg * 4 + r;
        pp[2048 + c] = sv[mf][r] + 128.f * bv[c];
      }
  }
  if (wave == 2) {
#pragma unroll
    for (int off = 1; off < 16; off <<= 1) {
#pragma unroll
      for (int r = 0; r < 4; ++r)
        kr[r] += __shfl_xor(kr[r], off);
    }
    if (l15 == 0) {
#pragma unroll
      for (int r = 0; r < 4; ++r)
        pp[2048 + 128 + cg * 4 + r] = kr[r];
    }
  }
}

// ---------------- cf (fallback) ----------------
__global__ __launch_bounds__(256) void cf_kernel(const float* __restrict__ x,
                                                 const float* __restrict__ bv,
                                                 const float* __restrict__ Kbuf,
                                                 const float* __restrict__ wvt,
                                                 float* __restrict__ part) {
  __shared__ float Vl[128 * 129];
  __shared__ float knl[16 * 132];
  int t   = threadIdx.x;
  int b   = blockIdx.y;
  int blk = blockIdx.x;
  const float* Kb = Kbuf + (size_t)b * 16 * NPIX;
  const float* xb = x + (size_t)b * 128 * NPIX;

  int m_own = t & 15;
  int c0    = (t >> 4) << 3;
  int pxg   = t & 15;

  float bvr[8];
#pragma unroll
  for (int jj = 0; jj < 8; ++jj) bvr[jj] = bv[c0 + jj];

  float macc[8] = {0,0,0,0,0,0,0,0};
  float vs[8]   = {0,0,0,0,0,0,0,0};
  float ksum[16];
#pragma unroll
  for (int m = 0; m < 16; ++m) ksum[m] = 0.f;

  for (int tile = blk; tile < 128; tile += 64) {
    __syncthreads();
    int pbase = tile << 7;

    if (t < 128) {
      float kv[16]; float ss = 0.f;
#pragma unroll
      for (int m = 0; m < 16; ++m) {
        kv[m] = Kb[(size_t)m * NPIX + pbase + t];
        ss = fmaf(kv[m], kv[m], ss);
      }
      float inv = rsqrtf(ss);
#pragma unroll
      for (int m = 0; m < 16; ++m) {
        float kn = kv[m] * inv;
        knl[m * 132 + t] = kn;
        ksum[m] += kn;
      }
    }

    float v[8][8];
#pragma unroll
    for (int i = 0; i < 8; ++i)
#pragma unroll
      for (int jj = 0; jj < 8; ++jj) v[i][jj] = 0.f;
    int px0 = pbase + (pxg << 3);
    for (int k = 0; k < 128; ++k) {
      const float4* xp = (const float4*)(xb + (size_t)k * NPIX + px0);
      float4 xa = xp[0], xc4 = xp[1];
      const float4* wp = (const float4*)(wvt + k * 128 + c0);
      float4 wa = wp[0], wc4 = wp[1];
      float xv[8] = {xa.x, xa.y, xa.z, xa.w, xc4.x, xc4.y, xc4.z, xc4.w};
      float wr[8] = {wa.x, wa.y, wa.z, wa.w, wc4.x, wc4.y, wc4.z, wc4.w};
#pragma unroll
      for (int i = 0; i < 8; ++i)
#pragma unroll
        for (int jj = 0; jj < 8; ++jj)
          v[i][jj] = fmaf(wr[i], xv[jj], v[i][jj]);
    }
#pragma unroll
    for (int i = 0; i < 8; ++i)
#pragma unroll
      for (int jj = 0; jj < 8; ++jj)
        Vl[(c0 + i) * 129 + (pxg << 3) + jj] = v[i][jj] + bvr[i];
    __syncthreads();

    for (int px = 0; px < 128; ++px) {
      float knv = knl[m_own * 132 + px];
      float vv[8];
#pragma unroll
      for (int jj = 0; jj < 8; ++jj) vv[jj] = Vl[(c0 + jj) * 129 + px];
#pragma unroll
      for (int jj = 0; jj < 8; ++jj) macc[jj] = fmaf(knv, vv[jj], macc[jj]);
      if (m_own == 0) {
#pragma unroll
        for (int jj = 0; jj < 8; ++jj) vs[jj] += vv[jj];
      }
    }
  }

  int blkid = b * 64 + blk;
  float* pp = part + (size_t)blkid * 2192;
#pragma unroll
  for (int jj = 0; jj < 8; ++jj) pp[m_own * 128 + c0 + jj] = macc[jj];
  if (m_own == 0) {
#pragma unroll
    for (int jj = 0; jj < 8; ++jj) pp[2048 + c0 + jj] = vs[jj];
  }
  __syncthreads();
  if (t < 128) {
#pragma unroll
    for (int m = 0; m < 16; ++m) knl[m * 132 + t] = ksum[m];
  }
  __syncthreads();
  if (t < 16) {
    float s = 0.f;
    for (int i = 0; i < 128; ++i) s += knl[t * 132 + i];
    pp[2048 + 128 + t] = s;
  }
}

// ---------------- reduce (fallback: 64 groups) ----------------
__global__ void reduce_kernel(const float* __restrict__ part, float* __restrict__ stats) {
  int b = blockIdx.y, t = threadIdx.x;
  int e = blockIdx.x * 256 + t;
  if (e >= 2192) return;
  const float* pp = part + (size_t)b * 64 * 2192;
  float s = 0.f;
  for (int g = 0; g < 64; ++g) s += pp[(size_t)g * 2192 + e];
  stats[(size_t)b * 2192 + e] = s;
}

// ---------------- reduce2 (mfma: 64 + 64 groups) ----------------
__global__ void reduce2_kernel(const float* __restrict__ part1,
                               const float* __restrict__ part2,
                               float* __restrict__ stats) {
  int b = blockIdx.y, t = threadIdx.x;
  int e = blockIdx.x * 256 + t;
  if (e >= 2192) return;
  const float* p1 = part1 + (size_t)b * 64 * 2192;
  const float* p2 = part2 + (size_t)b * 64 * 2192;
  float s = 0.f;
  for (int g = 0; g < 64; ++g) s += p1[(size_t)g * 2192 + e];
  for (int g = 0; g < 64; ++g) s += p2[(size_t)g * 2192 + e];
  stats[(size_t)b * 2192 + e] = s;
}

// ---------------- df: fused Q + tailor + final output (1 px/thread) ----------------
__global__ __launch_bounds__(256) void df_kernel(const float* __restrict__ stats,
                                                 const float* __restrict__ wq,
                                                 const float* __restrict__ bq,
                                                 const float* __restrict__ gamma,
                                                 float* __restrict__ out) {
  __shared__ float matl[128 * 16];
  __shared__ float wql[128 * 16];
  __shared__ float vsl[128];
  __shared__ float ksl[16];
  int t = threadIdx.x;
  int b = blockIdx.y;
  const float* st = stats + (size_t)b * 2192;
  for (int i = t; i < 2048; i += 256) {
    int m = i >> 7, c = i & 127;
    matl[c * 16 + m] = st[i];
    wql[c * 16 + m]  = wq[m * 128 + c];
  }
  if (t < 128) vsl[t] = st[2048 + t];
  if (t < 16)  ksl[t] = st[2048 + 128 + t] + EPS_V;
  __syncthreads();

  int px = blockIdx.x * 256 + t;
  float* ob = out + (size_t)b * 128 * NPIX;

  float q[16];
#pragma unroll
  for (int m = 0; m < 16; ++m) q[m] = bq[m];
  for (int c = 0; c < 128; ++c) {
    float xv = ob[(size_t)c * NPIX + px];
    const float4* wp = (const float4*)(wql + c * 16);
#pragma unroll
    for (int jj = 0; jj < 4; ++jj) {
      float4 w = wp[jj];
      q[jj*4+0] = fmaf(w.x, xv, q[jj*4+0]);
      q[jj*4+1] = fmaf(w.y, xv, q[jj*4+1]);
      q[jj*4+2] = fmaf(w.z, xv, q[jj*4+2]);
      q[jj*4+3] = fmaf(w.w, xv, q[jj*4+3]);
    }
  }
  float ss = 0.f;
#pragma unroll
  for (int m = 0; m < 16; ++m) ss = fmaf(q[m], q[m], ss);
  float inv = rsqrtf(ss);
#pragma unroll
  for (int m = 0; m < 16; ++m) q[m] *= inv;
  float den = (float)NPIX;
#pragma unroll
  for (int m = 0; m < 16; ++m) den = fmaf(q[m], ksl[m], den);
  float tl = gamma[0] / den;

  for (int c = 0; c < 128; ++c) {
    float s = vsl[c];
    const float4* mp = (const float4*)(matl + c * 16);
#pragma unroll
    for (int jj = 0; jj < 4; ++jj) {
      float4 w = mp[jj];
      s = fmaf(w.x, q[jj*4+0], s);
      s = fmaf(w.y, q[jj*4+1], s);
      s = fmaf(w.z, q[jj*4+2], s);
      s = fmaf(w.w, q[jj*4+3], s);
    }
    ob[(size_t)c * NPIX + px] = tl * s;
  }
}

extern "C" void kernel_launch(void* const* d_in, const int* in_sizes, int n_in,
                              void* d_out, int out_size, void* d_ws, size_t ws_size,
                              hipStream_t stream) {
  (void)in_sizes; (void)n_in; (void)out_size;
  const float* x   = (const float*)d_in[0];
  const float* w1  = (const float*)d_in[1];
  const float* w2  = (const float*)d_in[2];
  const float* w3  = (const float*)d_in[3];
  const float* w4  = (const float*)d_in[4];
  const float* bns = (const float*)d_in[5];
  const float* bnb = (const float*)d_in[6];
  const float* bnm = (const float*)d_in[7];
  const float* bnv = (const float*)d_in[8];
  const float* wq  = (const float*)d_in[9];
  const float* bq  = (const float*)d_in[10];
  const float* wk  = (const float*)d_in[11];
  const float* bk  = (const float*)d_in[12];
  const float* wv  = (const float*)d_in[13];
  const float* bv  = (const float*)d_in[14];
  const float* gm  = (const float*)d_in[15];
  float* ws  = (float*)d_ws;
  float* out = (float*)d_out;

  float* Kbuf = ws + OFF_K;
  float* w1f  = ws + OFF_W1F;
  float* wkt  = ws + OFF_WKT;
  float* wvt  = ws + OFF_WVT;
  float* bfp  = ws + OFF_BF;
  float* part = ws + OFF_PART;
  float* stat = ws + OFF_STATS;

  bool use_mfma = ws_size >= NEW_END * sizeof(float);
  if (use_mfma) {
    unsigned short* wbtr = (unsigned short*)(ws + OFF_WBT);
    unsigned short* xt   = (unsigned short*)(ws + OFF_XT);
    unsigned short* wvbr = (unsigned short*)(ws + OFF_WVB);
    unsigned short* zrow = (unsigned short*)(ws + OFF_ZROW);
    unsigned short* wxbr = (unsigned short*)(ws + OFF_K);   // first 6144 floats of K region
    float* part2 = ws + OFF_PART2;                          // K region tail (dead in mfma path)
    pa0_kernel<<<dim3(2112), 256, 0, stream>>>(x, xt, w1, w2, w3, w4,
                                               bns, bnb, bnm, bnv, wk, wv,
                                               wbtr, wvbr, wxbr, zrow, bfp);
    a2m_kernel<<<dim3(1536), 256, 0, stream>>>(xt, zrow, wbtr, bfp, out);
    cm_kernel<<<dim3(1024), 256, 0, stream>>>(xt, wvbr, wxbr, bv, bfp, bk, out, part, part2);
    reduce2_kernel<<<dim3(9, 8), 256, 0, stream>>>(part, part2, stat);
    df_kernel<<<dim3(64, 8), 256, 0, stream>>>(stat, wq, bq, gm, out);
  } else {
    float* w24t = ws + OFF_W24T;
    prep_common_kernel<<<64, 256, 0, stream>>>(w1, bns, bnb, bnm, bnv, wk, wv,
                                               w1f, wkt, wvt, bfp);
    prep_convf_kernel<<<64, 256, 0, stream>>>(w2, w3, w4, bns, bnv, w24t);
    a1_kernel<<<dim3(64, 8), 256, 0, stream>>>(x, w1f, wkt, bfp, bk, out, Kbuf);
    a2f_kernel<<<dim3(32, 8, 3), 256, 0, stream>>>(x, w24t, bfp, out);
    cf_kernel<<<dim3(64, 8), 256, 0, stream>>>(x, bv, Kbuf, wvt, part);
    reduce_kernel<<<dim3(9, 8), 256, 0, stream>>>(part, stat);
    df_kernel<<<dim3(64, 8), 256, 0, stream>>>(stat, wq, bq, gm, out);
  }
}

// Round 16
// 128.236 us; speedup vs baseline: 1.1124x; 1.0202x over previous
//
#include <hip/hip_runtime.h>
#include <hip/hip_bf16.h>
#include <math.h>

#define NPIX   16384
#define BATCH  8
#define BN_EPS 1e-5f
#define EPS_V  1e-6f

typedef __attribute__((ext_vector_type(8))) short bf16x8;
typedef __attribute__((ext_vector_type(4))) float f32x4;
typedef const __attribute__((address_space(1))) unsigned int* gas_ptr;
typedef __attribute__((address_space(3))) unsigned int* las_ptr;

// ---- workspace layout (float offsets) ----
#define OFF_K     ((size_t)0)          // fallback: Kbuf. mfma path: wxbr + part2
#define OFF_PART2 ((size_t)8192)       // mfma: 512*2192 = 1122304 (ends 1130496 < 2097152)
#define OFF_W1F   ((size_t)2097152)    // 128*32   = 4096
#define OFF_WKT   ((size_t)2101248)    // 128*16   = 2048
#define OFF_WVT   ((size_t)2103296)    // 128*128  = 16384
#define OFF_BF    ((size_t)2119680)    // 4*32     = 128
#define OFF_PART  ((size_t)2119808)    // 512*2192 = 1122304
#define OFF_STATS ((size_t)3242112)    // 8*2192   = 17536
#define BASE_END  ((size_t)3259648)
// mfma path extras
#define OFF_WBT   BASE_END             // 3*9*4*2*64*8 ushort = 55296 floats
#define OFF_XT    ((size_t)3314976)    // 8*4*16384*32 ushort = 8388608 floats (PRE-SWIZZLED)
#define OFF_WVB   ((size_t)11703584)   // 4*8*64*8 ushort = 8192 floats
#define OFF_ZROW  ((size_t)11711776)   // 4096 ushort zero row = 2048 floats
#define NEW_END   ((size_t)11713824)
// fallback extras
#define OFF_W24T  BASE_END             // 3*128*9*32 = 110592

__device__ inline unsigned short f2bf(float f) {
  union { float f; unsigned int u; } v; v.f = f;
  unsigned int r = (v.u + 0x7FFFu + ((v.u >> 16) & 1u)) >> 16;
  return (unsigned short)r;
}

// ---------------- prep_common (fallback path only) ----------------
__global__ void prep_common_kernel(const float* __restrict__ w1,
                                   const float* __restrict__ bns, const float* __restrict__ bnb,
                                   const float* __restrict__ bnm, const float* __restrict__ bnv,
                                   const float* __restrict__ wk, const float* __restrict__ wv,
                                   float* __restrict__ w1f, float* __restrict__ wkt,
                                   float* __restrict__ wvt, float* __restrict__ bf) {
  int tid = blockIdx.x * blockDim.x + threadIdx.x;
  int nt  = gridDim.x * blockDim.x;
  for (int i = tid; i < 128; i += nt) {
    float inv = bns[i] * rsqrtf(bnv[i] + BN_EPS);
    bf[i] = bnb[i] - bnm[i] * inv;
  }
  for (int i = tid; i < 4096; i += nt) {          // w1f[c][o]
    int c = i >> 5, o = i & 31;
    float inv = bns[o] * rsqrtf(bnv[o] + BN_EPS);
    w1f[i] = w1[o * 128 + c] * inv;
  }
  for (int i = tid; i < 2048; i += nt) {          // wkt[c][m]
    int c = i >> 4, m = i & 15;
    wkt[i] = wk[m * 128 + c];
  }
  for (int i = tid; i < 16384; i += nt) {         // wvt[c][o]
    int c = i >> 7, o = i & 127;
    wvt[i] = wv[o * 128 + c];
  }
}

// ---------------- pa0: merged a0 (blocks 0..2047) + prep_convb (blocks 2048..2111) ----------------
__global__ __launch_bounds__(256) void pa0_kernel(const float* __restrict__ x,
                                                  unsigned short* __restrict__ xt,
                                                  const float* __restrict__ w1,
                                                  const float* __restrict__ w2,
                                                  const float* __restrict__ w3,
                                                  const float* __restrict__ w4,
                                                  const float* __restrict__ bns,
                                                  const float* __restrict__ bnb,
                                                  const float* __restrict__ bnm,
                                                  const float* __restrict__ bnv,
                                                  const float* __restrict__ wk,
                                                  const float* __restrict__ wv,
                                                  unsigned short* __restrict__ wbtr,
                                                  unsigned short* __restrict__ wvbr,
                                                  unsigned short* __restrict__ wxbr,
                                                  unsigned short* __restrict__ zrow,
                                                  float* __restrict__ bf) {
  __shared__ unsigned short Ts[64][132];
  int t   = threadIdx.x;
  int idx = blockIdx.x;
  if (idx < 2048) {
    // ---- a0: transpose x -> xt bf16, quarter-major, pre-swizzled 16B units ----
    int b   = idx & 7;
    int px0 = (idx >> 3) * 64;
    const float* xb = x + (size_t)b * 128 * NPIX;
    int p = t & 63, cq = t >> 6;
#pragma unroll 8
    for (int i = 0; i < 32; ++i) {
      int c = cq * 32 + i;
      Ts[p][c] = f2bf(xb[(size_t)c * NPIX + px0 + p]);
    }
    __syncthreads();
    int pw = t >> 2, cg = t & 3;
    unsigned short* dst = xt + ((size_t)(b * 4 + cg) * 16384 + px0 + pw) * 32;
    int sw = (pw >> 1) & 3;
#pragma unroll
    for (int k = 0; k < 8; ++k) {
      uint2 v = *(const uint2*)(&Ts[pw][cg * 32 + k * 4]);
      int cgs = (k >> 1) ^ sw;
      *(uint2*)(dst + cgs * 8 + (k & 1) * 4) = v;
    }
  } else {
    // ---- prep_convb (grid-stride over 64 virtual blocks) ----
    int tid = (idx - 2048) * 256 + t;
    int nt  = 64 * 256;
    for (int i = tid; i < 128; i += nt) {
      float inv = bns[i] * rsqrtf(bnv[i] + BN_EPS);
      bf[i] = bnb[i] - bnm[i] * inv;
    }
    for (int i = tid; i < 4096; i += nt) zrow[i] = 0;
    for (int i = tid; i < 16384; i += nt) {
      int e = i & 7, lane = (i >> 3) & 63, f = (i >> 9) & 7, q = i >> 12;
      int oc = f * 16 + (lane & 15);
      int c  = q * 32 + (lane >> 4) * 8 + e;
      wvbr[i] = f2bf(wv[oc * 128 + c]);
    }
    for (int i = tid; i < 6144; i += nt) {
      int e = i & 7, lane = (i >> 3) & 63, ct = i >> 9;
      int tile = ct % 3, q = ct / 3;
      int c = q * 32 + (lane >> 4) * 8 + e;
      float val;
      if (tile < 2) {
        int oc = tile * 16 + (lane & 15);
        val = w1[oc * 128 + c] * (bns[oc] * rsqrtf(bnv[oc] + BN_EPS));
      } else {
        val = wk[(lane & 15) * 128 + c];
      }
      wxbr[i] = f2bf(val);
    }
    for (int i = tid; i < 110592; i += nt) {
      int br = i / 36864;
      int r  = i - br * 36864;
      int tap  = r >> 12;
      int r2   = r & 4095;
      int q    = r2 >> 10;
      int r3   = r2 & 1023;
      int pair = r3 >> 9;
      int r4   = r3 & 511;
      int lane = r4 >> 3, e = r4 & 7;
      int oc = pair * 16 + (lane & 15);
      int c  = q * 32 + (lane >> 4) * 8 + e;
      const float* w = (br == 0) ? w2 : ((br == 1) ? w3 : w4);
      int bo = (br + 1) * 32 + oc;
      float inv = bns[bo] * rsqrtf(bnv[bo] + BN_EPS);
      wbtr[i] = f2bf(w[(oc * 128 + c) * 9 + tap] * inv);
    }
  }
}

// ---------------- prep_convf (fallback) ----------------
__global__ void prep_convf_kernel(const float* __restrict__ w2, const float* __restrict__ w3,
                                  const float* __restrict__ w4,
                                  const float* __restrict__ bns, const float* __restrict__ bnv,
                                  float* __restrict__ w24t) {
  int tid = blockIdx.x * blockDim.x + threadIdx.x;
  int nt  = gridDim.x * blockDim.x;
  for (int i = tid; i < 110592; i += nt) {
    int br  = i / 36864;
    int rem = i - br * 36864;
    int c   = rem / 288;
    int k   = (rem % 288) >> 5;
    int o   = rem & 31;
    const float* w = (br == 0) ? w2 : ((br == 1) ? w3 : w4);
    int bo = (br + 1) * 32 + o;
    float inv = bns[bo] * rsqrtf(bnv[bo] + BN_EPS);
    w24t[i] = w[(o * 128 + c) * 9 + k] * inv;
  }
}

// ---------------- a1 (fallback only) ----------------
__global__ __launch_bounds__(256) void a1_kernel(const float* __restrict__ x,
                                                 const float* __restrict__ w1f,
                                                 const float* __restrict__ wkt,
                                                 const float* __restrict__ bfp,
                                                 const float* __restrict__ bk,
                                                 float* __restrict__ out,
                                                 float* __restrict__ Kbuf) {
  __shared__ float lw1[128 * 32];
  __shared__ float lwk[128 * 16];
  __shared__ float lbf[32];
  int t = threadIdx.x;
  for (int i = t; i < 4096; i += 256) lw1[i] = w1f[i];
  for (int i = t; i < 2048; i += 256) lwk[i] = wkt[i];
  if (t < 32) lbf[t] = bfp[t];
  __syncthreads();

  int b  = blockIdx.y;
  int px = blockIdx.x * 256 + t;
  const float* xb = x + (size_t)b * 128 * NPIX;

  float acc[48];
#pragma unroll
  for (int i = 0; i < 48; ++i) acc[i] = 0.f;

  for (int c = 0; c < 128; ++c) {
    float xv = xb[(size_t)c * NPIX + px];
    const float4* w1p = (const float4*)(lw1 + c * 32);
#pragma unroll
    for (int j = 0; j < 8; ++j) {
      float4 w = w1p[j];
      acc[j*4+0] = fmaf(w.x, xv, acc[j*4+0]);
      acc[j*4+1] = fmaf(w.y, xv, acc[j*4+1]);
      acc[j*4+2] = fmaf(w.z, xv, acc[j*4+2]);
      acc[j*4+3] = fmaf(w.w, xv, acc[j*4+3]);
    }
    const float4* wkp = (const float4*)(lwk + c * 16);
#pragma unroll
    for (int j = 0; j < 4; ++j) {
      float4 w = wkp[j];
      acc[32+j*4+0] = fmaf(w.x, xv, acc[32+j*4+0]);
      acc[32+j*4+1] = fmaf(w.y, xv, acc[32+j*4+1]);
      acc[32+j*4+2] = fmaf(w.z, xv, acc[32+j*4+2]);
      acc[32+j*4+3] = fmaf(w.w, xv, acc[32+j*4+3]);
    }
  }
#pragma unroll
  for (int o = 0; o < 32; ++o)
    out[((size_t)(b * 128 + o)) * NPIX + px] = fmaxf(acc[o] + lbf[o], 0.f);
#pragma unroll
  for (int m = 0; m < 16; ++m)
    Kbuf[((size_t)(b * 16 + m)) * NPIX + px] = acc[32 + m] + bk[m];
}

// ---------------- a2m (round-11 body): 3x16KB buffers, counted-vmcnt 2-deep pipeline ----------------
__global__ __launch_bounds__(256) void a2m_kernel(const unsigned short* __restrict__ xt,
                                                  const unsigned short* __restrict__ zrow,
                                                  const unsigned short* __restrict__ wbtr,
                                                  const float* __restrict__ bfp,
                                                  float* __restrict__ out) {
  __shared__ unsigned short sx[3 * 8192 + 8];   // 3x16KB sub-buffers + 16B zero page @byte 49152
  int t    = threadIdx.x;
  int wave = t >> 6, lane = t & 63;
  int l15  = lane & 15, cg = lane >> 4;
  int idx  = blockIdx.x;
  int b    = idx & 7;                           // batch -> XCD
  int rest = idx >> 3;
  int h2   = rest & 63;
  int br   = rest >> 6;
  int d    = 6 * (br + 1);
  int h0   = h2 * 2;
  int j    = wave >> 1;                         // row of the pair this wave computes/stages
  int whalf = wave & 1;                         // px half (compute) / row half (stage)
  int p0   = whalf * 64;

  if (t == 0) *(uint4*)(sx + 24576) = make_uint4(0u, 0u, 0u, 0u);

  const unsigned short* wb    = wbtr + (size_t)br * 36864;
  const unsigned short* slabs = xt + (size_t)b * 4 * 524288;

  f32x4 acc[2][4];
#pragma unroll
  for (int i = 0; i < 2; ++i)
#pragma unroll
    for (int n = 0; n < 4; ++n) acc[i][n] = (f32x4){0.f, 0.f, 0.f, 0.f};

  int pxb[3], xorv[3];
#pragma unroll
  for (int kw = 0; kw < 3; ++kw) {
    pxb[kw]  = p0 + l15 + (kw - 1) * d;
    xorv[kw] = (cg ^ ((pxb[kw] >> 1) & 3)) << 4;
  }

  auto STAGE = [&](int s) {
    int q = s / 3, kh = s % 3;
    int srow = h0 + j + (kh - 1) * d;
    const unsigned short* rowsrc =
        ((unsigned)srow < 128u) ? (slabs + (size_t)q * 524288 + (size_t)srow * 4096)
                                : zrow;
    const unsigned short* gsrc = rowsrc + whalf * 2048 + lane * 8;
    unsigned short* lbase = sx + (s % 3) * 8192 + j * 4096 + whalf * 2048;
#pragma unroll
    for (int k = 0; k < 4; ++k)
      __builtin_amdgcn_global_load_lds((gas_ptr)(const void*)(gsrc + k * 512),
                                       (las_ptr)(void*)(lbase + k * 512), 16, 0, 0);
  };

  auto COMPUTE = [&](int s) {
    int q = s / 3, kh = s % 3;
    int bb = (s % 3) * 16384 + j * 8192;        // byte base of this wave's row
    bf16x8 a[3][2];
#pragma unroll
    for (int kw = 0; kw < 3; ++kw) {
      int tap = kh * 3 + kw;
      const unsigned short* wt = wb + ((((size_t)tap * 4 + q) * 2) << 9);
      a[kw][0] = *(const bf16x8*)(wt + lane * 8);
      a[kw][1] = *(const bf16x8*)(wt + 512 + lane * 8);
    }
#pragma unroll
    for (int kw = 0; kw < 3; ++kw) {
      int base = bb + pxb[kw] * 64 + xorv[kw];
#pragma unroll
      for (int nf = 0; nf < 4; ++nf) {
        int px   = pxb[kw] + nf * 16;
        int addr = ((unsigned)px < 128u) ? (base + nf * 1024) : 49152;
        bf16x8 bv = *(const bf16x8*)((const char*)sx + addr);
        acc[0][nf] = __builtin_amdgcn_mfma_f32_16x16x32_bf16(a[kw][0], bv, acc[0][nf], 0, 0, 0);
        acc[1][nf] = __builtin_amdgcn_mfma_f32_16x16x32_bf16(a[kw][1], bv, acc[1][nf], 0, 0, 0);
      }
    }
  };

  STAGE(0);
  STAGE(1);
  __syncthreads();                              // full drain once: buffers 0,1 ready; zero page visible
  for (int s = 0; s < 12; ++s) {
    COMPUTE(s);
    if (s < 10) STAGE(s + 2);                   // keep 2 stages in flight
    if (s < 11) {
      if (s < 10) asm volatile("s_waitcnt vmcnt(4)" ::: "memory");
      else        asm volatile("s_waitcnt vmcnt(0)" ::: "memory");
      __builtin_amdgcn_s_barrier();
      __builtin_amdgcn_sched_barrier(0);
    }
  }

  int ocb = (br + 1) * 32;
  int pxw = (h0 + j) * 128 + p0;
#pragma unroll
  for (int mf = 0; mf < 2; ++mf) {
#pragma unroll
    for (int r = 0; r < 4; ++r) {
      int oc = mf * 16 + cg * 4 + r;
      float bias = bfp[ocb + oc];
      float* op = out + ((size_t)(b * 128 + ocb + oc)) * NPIX + pxw + l15;
#pragma unroll
      for (int nf = 0; nf < 4; ++nf)
        op[nf * 16] = fmaxf(acc[mf][nf][r] + bias, 0.f);
    }
  }
}

// ---------------- a2f (fallback) ----------------
__global__ __launch_bounds__(256) void a2f_kernel(const float* __restrict__ x,
                                                  const float* __restrict__ w24t,
                                                  const float* __restrict__ bfp,
                                                  float* __restrict__ out) {
  int t  = threadIdx.x;
  int og = t & 3;
  int pg = (t >> 2) & 15;
  int r  = t >> 6;
  int br = blockIdx.z;
  int b  = blockIdx.y;
  int h  = blockIdx.x * 4 + r;
  int d  = 6 * (br + 1);

  const float* wt = w24t + (size_t)br * 36864;
  const float* bf = bfp + (br + 1) * 32;
  const float* xb = x + (size_t)b * 128 * NPIX;
  int w0 = pg << 3;

  float acc[8][8];
#pragma unroll
  for (int p = 0; p < 8; ++p)
#pragma unroll
    for (int o = 0; o < 8; ++o) acc[p][o] = 0.f;

  for (int c = 0; c < 128; ++c) {
    const float* xc = xb + (size_t)c * NPIX;
    const float* wc = wt + c * 288;
#pragma unroll
    for (int kh = 0; kh < 3; ++kh) {
      int row = h + (kh - 1) * d;
      if ((unsigned)row >= 128u) continue;
      const float* xr = xc + row * 128;
#pragma unroll
      for (int kw = 0; kw < 3; ++kw) {
        int wb = w0 + (kw - 1) * d;
        float xv[8];
        if (wb >= 0 && wb <= 120) {
          const float2* p2 = (const float2*)(xr + wb);
#pragma unroll
          for (int jj = 0; jj < 4; ++jj) {
            float2 v = p2[jj];
            xv[2*jj] = v.x; xv[2*jj+1] = v.y;
          }
        } else {
#pragma unroll
          for (int jj = 0; jj < 8; ++jj) {
            int ww = wb + jj;
            xv[jj] = ((unsigned)ww < 128u) ? xr[ww] : 0.f;
          }
        }
        const float4* wp = (const float4*)(wc + (kh * 3 + kw) * 32 + og * 8);
        float4 wa = wp[0], wbv = wp[1];
        float wr[8] = {wa.x, wa.y, wa.z, wa.w, wbv.x, wbv.y, wbv.z, wbv.w};
#pragma unroll
        for (int p = 0; p < 8; ++p)
#pragma unroll
          for (int o = 0; o < 8; ++o)
            acc[p][o] = fmaf(xv[p], wr[o], acc[p][o]);
      }
    }
  }

  int chbase = (br + 1) * 32 + og * 8;
  int n = h * 128 + w0;
#pragma unroll
  for (int o = 0; o < 8; ++o) {
    float bias = bf[og * 8 + o];
    float* op = out + ((size_t)(b * 128 + chbase + o)) * NPIX + n;
    float4 v0 = make_float4(fmaxf(acc[0][o] + bias, 0.f), fmaxf(acc[1][o] + bias, 0.f),
                            fmaxf(acc[2][o] + bias, 0.f), fmaxf(acc[3][o] + bias, 0.f));
    float4 v1 = make_float4(fmaxf(acc[4][o] + bias, 0.f), fmaxf(acc[5][o] + bias, 0.f),
                            fmaxf(acc[6][o] + bias, 0.f), fmaxf(acc[7][o] + bias, 0.f));
    ((float4*)op)[0] = v0;
    ((float4*)op)[1] = v1;
  }
}

// ---------------- cm v7: 1 tile/block, batch->XCD swizzle, swizzled-xt reads ----------------
__global__ __launch_bounds__(256) void cm_kernel(const unsigned short* __restrict__ xt,
                                                 const unsigned short* __restrict__ wvbr,
                                                 const unsigned short* __restrict__ wxbr,
                                                 const float* __restrict__ bv,
                                                 const float* __restrict__ bfp,
                                                 const float* __restrict__ bk,
                                                 float* __restrict__ out,
                                                 float* __restrict__ part1,
                                                 float* __restrict__ part2) {
  __shared__ __align__(16) unsigned short Vl[128 * 136];   // bf16 [oc][px]
  __shared__ __align__(16) unsigned short knl[16 * 136];   // bf16 [m][px]
  int t    = threadIdx.x;
  int idx  = blockIdx.x;
  int b    = idx & 7;           // batch -> XCD (1024 % 8 == 0, bijective)
  int blk  = idx >> 3;          // 0..127 == tile
  int wave = t >> 6, lane = t & 63;
  int l15  = lane & 15, cg = lane >> 4;
  int ocb  = wave * 32;
  int pbase = blk << 7;
  int cgsw = (cg ^ ((l15 >> 1) & 3)) << 3;   // swizzled-xt unit offset (ushorts)

  float bvr[2][4];
#pragma unroll
  for (int mf = 0; mf < 2; ++mf)
#pragma unroll
    for (int r = 0; r < 4; ++r) bvr[mf][r] = bv[ocb + mf * 16 + cg * 4 + r];

  float xb4[4];
#pragma unroll
  for (int r = 0; r < 4; ++r) xb4[r] = 0.f;
  if (wave == 0) {
#pragma unroll
    for (int r = 0; r < 4; ++r) xb4[r] = bfp[cg * 4 + r];
  } else if (wave == 1) {
#pragma unroll
    for (int r = 0; r < 4; ++r) xb4[r] = bfp[16 + cg * 4 + r];
  } else if (wave == 2) {
#pragma unroll
    for (int r = 0; r < 4; ++r) xb4[r] = bk[cg * 4 + r];
  }
  int xwave = (wave < 3) ? wave : 0;

  float kr[4] = {0.f, 0.f, 0.f, 0.f};
  float sv[2][4];
#pragma unroll
  for (int mf = 0; mf < 2; ++mf)
#pragma unroll
    for (int r = 0; r < 4; ++r) sv[mf][r] = 0.f;
  f32x4 am[2];
  am[0] = (f32x4){0.f,0.f,0.f,0.f};
  am[1] = (f32x4){0.f,0.f,0.f,0.f};

#pragma unroll
  for (int hf = 0; hf < 2; ++hf) {
    f32x4 vacc[2][4];
    f32x4 xacc[4];
#pragma unroll
    for (int i = 0; i < 2; ++i)
#pragma unroll
      for (int n = 0; n < 4; ++n) vacc[i][n] = (f32x4){0.f,0.f,0.f,0.f};
#pragma unroll
    for (int n = 0; n < 4; ++n) xacc[n] = (f32x4){0.f,0.f,0.f,0.f};

#pragma unroll
    for (int cc = 0; cc < 4; ++cc) {
      const unsigned short* xq = xt + ((size_t)(b * 4 + cc) * 16384 + pbase) * 32;
      bf16x8 a0 = *(const bf16x8*)(wvbr + ((cc * 8 + wave * 2 + 0) << 9) + lane * 8);
      bf16x8 a1 = *(const bf16x8*)(wvbr + ((cc * 8 + wave * 2 + 1) << 9) + lane * 8);
      bf16x8 ax = *(const bf16x8*)(wxbr + ((cc * 3 + xwave) << 9) + lane * 8);
#pragma unroll
      for (int nf = 0; nf < 4; ++nf) {
        int nfg = hf * 4 + nf;
        bf16x8 bx = *(const bf16x8*)(xq + (size_t)(nfg * 16 + l15) * 32 + cgsw);
        vacc[0][nf] = __builtin_amdgcn_mfma_f32_16x16x32_bf16(a0, bx, vacc[0][nf], 0, 0, 0);
        vacc[1][nf] = __builtin_amdgcn_mfma_f32_16x16x32_bf16(a1, bx, vacc[1][nf], 0, 0, 0);
        if (wave < 3)
          xacc[nf] = __builtin_amdgcn_mfma_f32_16x16x32_bf16(ax, bx, xacc[nf], 0, 0, 0);
      }
    }

#pragma unroll
    for (int mf = 0; mf < 2; ++mf) {
#pragma unroll
      for (int r = 0; r < 4; ++r) {
        float s = 0.f;
#pragma unroll
        for (int nf = 0; nf < 4; ++nf) s += vacc[mf][nf][r];
        sv[mf][r] += s;
        int c = ocb + mf * 16 + cg * 4 + r;
#pragma unroll
        for (int nf = 0; nf < 4; ++nf)
          Vl[c * 136 + (hf * 4 + nf) * 16 + l15] = f2bf(vacc[mf][nf][r] + bvr[mf][r]);
      }
    }

    if (wave < 2) {
#pragma unroll
      for (int r = 0; r < 4; ++r) {
        int oc = wave * 16 + cg * 4 + r;
        float* op = out + ((size_t)(b * 128 + oc)) * NPIX + pbase + l15;
#pragma unroll
        for (int nf = 0; nf < 4; ++nf)
          op[(hf * 4 + nf) * 16] = fmaxf(xacc[nf][r] + xb4[r], 0.f);
      }
    } else if (wave == 2) {
#pragma unroll
      for (int nf = 0; nf < 4; ++nf) {
        int nfg = hf * 4 + nf;
        float kq[4]; float s2 = 0.f;
#pragma unroll
        for (int r = 0; r < 4; ++r) {
          kq[r] = xacc[nf][r] + xb4[r];
          s2 = fmaf(kq[r], kq[r], s2);
        }
        s2 += __shfl_xor(s2, 16);
        s2 += __shfl_xor(s2, 32);
        float inv = rsqrtf(s2);
#pragma unroll
        for (int r = 0; r < 4; ++r) {
          float kn = kq[r] * inv;
          knl[(cg * 4 + r) * 136 + nfg * 16 + l15] = f2bf(kn);
          kr[r] += kn;
        }
      }
    }
  }
  __syncthreads();

#pragma unroll
  for (int ks = 0; ks < 4; ++ks) {
    bf16x8 af = *(const bf16x8*)(knl + l15 * 136 + ks * 32 + cg * 8);
    bf16x8 b0 = *(const bf16x8*)(Vl + (size_t)(ocb + l15) * 136 + ks * 32 + cg * 8);
    bf16x8 b1 = *(const bf16x8*)(Vl + (size_t)(ocb + 16 + l15) * 136 + ks * 32 + cg * 8);
    am[0] = __builtin_amdgcn_mfma_f32_16x16x32_bf16(af, b0, am[0], 0, 0, 0);
    am[1] = __builtin_amdgcn_mfma_f32_16x16x32_bf16(af, b1, am[1], 0, 0, 0);
  }

  float* pp = (blk < 64) ? (part1 + ((size_t)b * 64 + blk) * 2192)
                         : (part2 + ((size_t)b * 64 + (blk - 64)) * 2192);
#pragma unroll
  for (int nf2 = 0; nf2 < 2; ++nf2)
#pragma unroll
    for (int r = 0; r < 4; ++r)
      pp[(cg * 4 + r) * 128 + ocb + nf2 * 16 + l15] = am[nf2][r];
#pragma unroll
  for (int off = 1; off < 16; off <<= 1) {
#pragma unroll
    for (int mf = 0; mf < 2; ++mf)
#pragma unroll
      for (int r = 0; r < 4; ++r)
        sv[mf][r] += __shfl_xor(sv[mf][r], off);
  }
  if (l15 == 0) {
#pragma unroll
    for (int mf = 0; mf < 2; ++mf)
#pragma unroll
      for (int r = 0; r < 4; ++r) {
        int c = ocb + mf * 16 + cg * 4 + r;
        pp[2048 + c] = sv[mf][r] + 128.f * bv[c];
      }
  }
  if (wave == 2) {
#pragma unroll
    for (int off = 1; off < 16; off <<= 1) {
#pragma unroll
      for (int r = 0; r < 4; ++r)
        kr[r] += __shfl_xor(kr[r], off);
    }
    if (l15 == 0) {
#pragma unroll
      for (int r = 0; r < 4; ++r)
        pp[2048 + 128 + cg * 4 + r] = kr[r];
    }
  }
}

// ---------------- cf (fallback) ----------------
__global__ __launch_bounds__(256) void cf_kernel(const float* __restrict__ x,
                                                 const float* __restrict__ bv,
                                                 const float* __restrict__ Kbuf,
                                                 const float* __restrict__ wvt,
                                                 float* __restrict__ part) {
  __shared__ float Vl[128 * 129];
  __shared__ float knl[16 * 132];
  int t   = threadIdx.x;
  int b   = blockIdx.y;
  int blk = blockIdx.x;
  const float* Kb = Kbuf + (size_t)b * 16 * NPIX;
  const float* xb = x + (size_t)b * 128 * NPIX;

  int m_own = t & 15;
  int c0    = (t >> 4) << 3;
  int pxg   = t & 15;

  float bvr[8];
#pragma unroll
  for (int jj = 0; jj < 8; ++jj) bvr[jj] = bv[c0 + jj];

  float macc[8] = {0,0,0,0,0,0,0,0};
  float vs[8]   = {0,0,0,0,0,0,0,0};
  float ksum[16];
#pragma unroll
  for (int m = 0; m < 16; ++m) ksum[m] = 0.f;

  for (int tile = blk; tile < 128; tile += 64) {
    __syncthreads();
    int pbase = tile << 7;

    if (t < 128) {
      float kv[16]; float ss = 0.f;
#pragma unroll
      for (int m = 0; m < 16; ++m) {
        kv[m] = Kb[(size_t)m * NPIX + pbase + t];
        ss = fmaf(kv[m], kv[m], ss);
      }
      float inv = rsqrtf(ss);
#pragma unroll
      for (int m = 0; m < 16; ++m) {
        float kn = kv[m] * inv;
        knl[m * 132 + t] = kn;
        ksum[m] += kn;
      }
    }

    float v[8][8];
#pragma unroll
    for (int i = 0; i < 8; ++i)
#pragma unroll
      for (int jj = 0; jj < 8; ++jj) v[i][jj] = 0.f;
    int px0 = pbase + (pxg << 3);
    for (int k = 0; k < 128; ++k) {
      const float4* xp = (const float4*)(xb + (size_t)k * NPIX + px0);
      float4 xa = xp[0], xc4 = xp[1];
      const float4* wp = (const float4*)(wvt + k * 128 + c0);
      float4 wa = wp[0], wc4 = wp[1];
      float xv[8] = {xa.x, xa.y, xa.z, xa.w, xc4.x, xc4.y, xc4.z, xc4.w};
      float wr[8] = {wa.x, wa.y, wa.z, wa.w, wc4.x, wc4.y, wc4.z, wc4.w};
#pragma unroll
      for (int i = 0; i < 8; ++i)
#pragma unroll
        for (int jj = 0; jj < 8; ++jj)
          v[i][jj] = fmaf(wr[i], xv[jj], v[i][jj]);
    }
#pragma unroll
    for (int i = 0; i < 8; ++i)
#pragma unroll
      for (int jj = 0; jj < 8; ++jj)
        Vl[(c0 + i) * 129 + (pxg << 3) + jj] = v[i][jj] + bvr[i];
    __syncthreads();

    for (int px = 0; px < 128; ++px) {
      float knv = knl[m_own * 132 + px];
      float vv[8];
#pragma unroll
      for (int jj = 0; jj < 8; ++jj) vv[jj] = Vl[(c0 + jj) * 129 + px];
#pragma unroll
      for (int jj = 0; jj < 8; ++jj) macc[jj] = fmaf(knv, vv[jj], macc[jj]);
      if (m_own == 0) {
#pragma unroll
        for (int jj = 0; jj < 8; ++jj) vs[jj] += vv[jj];
      }
    }
  }

  int blkid = b * 64 + blk;
  float* pp = part + (size_t)blkid * 2192;
#pragma unroll
  for (int jj = 0; jj < 8; ++jj) pp[m_own * 128 + c0 + jj] = macc[jj];
  if (m_own == 0) {
#pragma unroll
    for (int jj = 0; jj < 8; ++jj) pp[2048 + c0 + jj] = vs[jj];
  }
  __syncthreads();
  if (t < 128) {
#pragma unroll
    for (int m = 0; m < 16; ++m) knl[m * 132 + t] = ksum[m];
  }
  __syncthreads();
  if (t < 16) {
    float s = 0.f;
    for (int i = 0; i < 128; ++i) s += knl[t * 132 + i];
    pp[2048 + 128 + t] = s;
  }
}

// ---------------- reduce (fallback: 64 groups) ----------------
__global__ void reduce_kernel(const float* __restrict__ part, float* __restrict__ stats) {
  int b = blockIdx.y, t = threadIdx.x;
  int e = blockIdx.x * 256 + t;
  if (e >= 2192) return;
  const float* pp = part + (size_t)b * 64 * 2192;
  float s = 0.f;
  for (int g = 0; g < 64; ++g) s += pp[(size_t)g * 2192 + e];
  stats[(size_t)b * 2192 + e] = s;
}

// ---------------- reduce2 (mfma: 64 + 64 groups) ----------------
__global__ void reduce2_kernel(const float* __restrict__ part1,
                               const float* __restrict__ part2,
                               float* __restrict__ stats) {
  int b = blockIdx.y, t = threadIdx.x;
  int e = blockIdx.x * 256 + t;
  if (e >= 2192) return;
  const float* p1 = part1 + (size_t)b * 64 * 2192;
  const float* p2 = part2 + (size_t)b * 64 * 2192;
  float s = 0.f;
  for (int g = 0; g < 64; ++g) s += p1[(size_t)g * 2192 + e];
  for (int g = 0; g < 64; ++g) s += p2[(size_t)g * 2192 + e];
  stats[(size_t)b * 2192 + e] = s;
}

// ---------------- df v2: fused final pass, c-split thread pairs (1024 blocks) ----------------
// Block = 128 px, 256 threads: half h handles channels [h*64, h*64+64) for both the
// Q-accumulate (partials exchanged via LDS) and the output write. Disjoint px per block;
// all out-reads precede the barrier before any out-write -> no hazard.
__global__ __launch_bounds__(256) void df_kernel(const float* __restrict__ stats,
                                                 const float* __restrict__ wq,
                                                 const float* __restrict__ bq,
                                                 const float* __restrict__ gamma,
                                                 float* __restrict__ out) {
  __shared__ float matl[128 * 16];
  __shared__ float wql[128 * 16];
  __shared__ float vsl[128];
  __shared__ float ksl[16];
  __shared__ float qex[16][2][128];
  int t = threadIdx.x;
  int b = blockIdx.y;
  const float* st = stats + (size_t)b * 2192;
  for (int i = t; i < 2048; i += 256) {
    int m = i >> 7, c = i & 127;
    matl[c * 16 + m] = st[i];
    wql[c * 16 + m]  = wq[m * 128 + c];
  }
  if (t < 128) vsl[t] = st[2048 + t];
  if (t < 16)  ksl[t] = st[2048 + 128 + t] + EPS_V;
  __syncthreads();

  int pxl  = t & 127, half = t >> 7;
  int px   = blockIdx.x * 128 + pxl;
  int cbeg = half * 64;
  float* ob = out + (size_t)b * 128 * NPIX;

  // Q partial over this half's 64 channels (bq added by half 0 only)
  float q[16];
#pragma unroll
  for (int m = 0; m < 16; ++m) q[m] = (half == 0) ? bq[m] : 0.f;
  for (int c = cbeg; c < cbeg + 64; ++c) {
    float xv = ob[(size_t)c * NPIX + px];
    const float4* wp = (const float4*)(wql + c * 16);
#pragma unroll
    for (int jj = 0; jj < 4; ++jj) {
      float4 w = wp[jj];
      q[jj*4+0] = fmaf(w.x, xv, q[jj*4+0]);
      q[jj*4+1] = fmaf(w.y, xv, q[jj*4+1]);
      q[jj*4+2] = fmaf(w.z, xv, q[jj*4+2]);
      q[jj*4+3] = fmaf(w.w, xv, q[jj*4+3]);
    }
  }
#pragma unroll
  for (int m = 0; m < 16; ++m) qex[m][half][pxl] = q[m];
  __syncthreads();   // also fences: all out-reads done before any out-write below
#pragma unroll
  for (int m = 0; m < 16; ++m) q[m] = qex[m][0][pxl] + qex[m][1][pxl];

  float ss = 0.f;
#pragma unroll
  for (int m = 0; m < 16; ++m) ss = fmaf(q[m], q[m], ss);
  float inv = rsqrtf(ss);
#pragma unroll
  for (int m = 0; m < 16; ++m) q[m] *= inv;
  float den = (float)NPIX;
#pragma unroll
  for (int m = 0; m < 16; ++m) den = fmaf(q[m], ksl[m], den);
  float tl = gamma[0] / den;

  for (int c = cbeg; c < cbeg + 64; ++c) {
    float s = vsl[c];
    const float4* mp = (const float4*)(matl + c * 16);
#pragma unroll
    for (int jj = 0; jj < 4; ++jj) {
      float4 w = mp[jj];
      s = fmaf(w.x, q[jj*4+0], s);
      s = fmaf(w.y, q[jj*4+1], s);
      s = fmaf(w.z, q[jj*4+2], s);
      s = fmaf(w.w, q[jj*4+3], s);
    }
    ob[(size_t)c * NPIX + px] = tl * s;
  }
}

extern "C" void kernel_launch(void* const* d_in, const int* in_sizes, int n_in,
                              void* d_out, int out_size, void* d_ws, size_t ws_size,
                              hipStream_t stream) {
  (void)in_sizes; (void)n_in; (void)out_size;
  const float* x   = (const float*)d_in[0];
  const float* w1  = (const float*)d_in[1];
  const float* w2  = (const float*)d_in[2];
  const float* w3  = (const float*)d_in[3];
  const float* w4  = (const float*)d_in[4];
  const float* bns = (const float*)d_in[5];
  const float* bnb = (const float*)d_in[6];
  const float* bnm = (const float*)d_in[7];
  const float* bnv = (const float*)d_in[8];
  const float* wq  = (const float*)d_in[9];
  const float* bq  = (const float*)d_in[10];
  const float* wk  = (const float*)d_in[11];
  const float* bk  = (const float*)d_in[12];
  const float* wv  = (const float*)d_in[13];
  const float* bv  = (const float*)d_in[14];
  const float* gm  = (const float*)d_in[15];
  float* ws  = (float*)d_ws;
  float* out = (float*)d_out;

  float* Kbuf = ws + OFF_K;
  float* w1f  = ws + OFF_W1F;
  float* wkt  = ws + OFF_WKT;
  float* wvt  = ws + OFF_WVT;
  float* bfp  = ws + OFF_BF;
  float* part = ws + OFF_PART;
  float* stat = ws + OFF_STATS;

  bool use_mfma = ws_size >= NEW_END * sizeof(float);
  if (use_mfma) {
    unsigned short* wbtr = (unsigned short*)(ws + OFF_WBT);
    unsigned short* xt   = (unsigned short*)(ws + OFF_XT);
    unsigned short* wvbr = (unsigned short*)(ws + OFF_WVB);
    unsigned short* zrow = (unsigned short*)(ws + OFF_ZROW);
    unsigned short* wxbr = (unsigned short*)(ws + OFF_K);   // first 6144 floats of K region
    float* part2 = ws + OFF_PART2;                          // K region tail (dead in mfma path)
    pa0_kernel<<<dim3(2112), 256, 0, stream>>>(x, xt, w1, w2, w3, w4,
                                               bns, bnb, bnm, bnv, wk, wv,
                                               wbtr, wvbr, wxbr, zrow, bfp);
    a2m_kernel<<<dim3(1536), 256, 0, stream>>>(xt, zrow, wbtr, bfp, out);
    cm_kernel<<<dim3(1024), 256, 0, stream>>>(xt, wvbr, wxbr, bv, bfp, bk, out, part, part2);
    reduce2_kernel<<<dim3(9, 8), 256, 0, stream>>>(part, part2, stat);
    df_kernel<<<dim3(128, 8), 256, 0, stream>>>(stat, wq, bq, gm, out);
  } else {
    float* w24t = ws + OFF_W24T;
    prep_common_kernel<<<64, 256, 0, stream>>>(w1, bns, bnb, bnm, bnv, wk, wv,
                                               w1f, wkt, wvt, bfp);
    prep_convf_kernel<<<64, 256, 0, stream>>>(w2, w3, w4, bns, bnv, w24t);
    a1_kernel<<<dim3(64, 8), 256, 0, stream>>>(x, w1f, wkt, bfp, bk, out, Kbuf);
    a2f_kernel<<<dim3(32, 8, 3), 256, 0, stream>>>(x, w24t, bfp, out);
    cf_kernel<<<dim3(64, 8), 256, 0, stream>>>(x, bv, Kbuf, wvt, part);
    reduce_kernel<<<dim3(9, 8), 256, 0, stream>>>(part, stat);
    df_kernel<<<dim3(128, 8), 256, 0, stream>>>(stat, wq, bq, gm, out);
  }
}

// Round 17
// 123.730 us; speedup vs baseline: 1.1529x; 1.0364x over previous
//
#include <hip/hip_runtime.h>
#include <hip/hip_bf16.h>
#include <math.h>

#define NPIX   16384
#define BATCH  8
#define BN_EPS 1e-5f
#define EPS_V  1e-6f

typedef __attribute__((ext_vector_type(8))) short bf16x8;
typedef __attribute__((ext_vector_type(4))) float f32x4;
typedef const __attribute__((address_space(1))) unsigned int* gas_ptr;
typedef __attribute__((address_space(3))) unsigned int* las_ptr;

// ---- workspace layout (float offsets) ----
#define OFF_K     ((size_t)0)          // fallback: Kbuf. mfma path: wxbr + part2
#define OFF_PART2 ((size_t)8192)       // mfma: 512*2192 = 1122304 (ends 1130496 < 2097152)
#define OFF_W1F   ((size_t)2097152)    // 128*32   = 4096
#define OFF_WKT   ((size_t)2101248)    // 128*16   = 2048
#define OFF_WVT   ((size_t)2103296)    // 128*128  = 16384
#define OFF_BF    ((size_t)2119680)    // 4*32     = 128
#define OFF_PART  ((size_t)2119808)    // 512*2192 = 1122304
#define OFF_STATS ((size_t)3242112)    // 8*2192   = 17536
#define BASE_END  ((size_t)3259648)
// mfma path extras
#define OFF_WBT   BASE_END             // 3*9*4*2*64*8 ushort = 55296 floats
#define OFF_XT    ((size_t)3314976)    // 8*4*16384*32 ushort = 8388608 floats (PRE-SWIZZLED)
#define OFF_WVB   ((size_t)11703584)   // 4*8*64*8 ushort = 8192 floats
#define OFF_ZROW  ((size_t)11711776)   // 4096 ushort zero row = 2048 floats
#define NEW_END   ((size_t)11713824)
// fallback extras
#define OFF_W24T  BASE_END             // 3*128*9*32 = 110592

__device__ inline unsigned short f2bf(float f) {
  union { float f; unsigned int u; } v; v.f = f;
  unsigned int r = (v.u + 0x7FFFu + ((v.u >> 16) & 1u)) >> 16;
  return (unsigned short)r;
}

// ---------------- prep_common (fallback path only) ----------------
__global__ void prep_common_kernel(const float* __restrict__ w1,
                                   const float* __restrict__ bns, const float* __restrict__ bnb,
                                   const float* __restrict__ bnm, const float* __restrict__ bnv,
                                   const float* __restrict__ wk, const float* __restrict__ wv,
                                   float* __restrict__ w1f, float* __restrict__ wkt,
                                   float* __restrict__ wvt, float* __restrict__ bf) {
  int tid = blockIdx.x * blockDim.x + threadIdx.x;
  int nt  = gridDim.x * blockDim.x;
  for (int i = tid; i < 128; i += nt) {
    float inv = bns[i] * rsqrtf(bnv[i] + BN_EPS);
    bf[i] = bnb[i] - bnm[i] * inv;
  }
  for (int i = tid; i < 4096; i += nt) {          // w1f[c][o]
    int c = i >> 5, o = i & 31;
    float inv = bns[o] * rsqrtf(bnv[o] + BN_EPS);
    w1f[i] = w1[o * 128 + c] * inv;
  }
  for (int i = tid; i < 2048; i += nt) {          // wkt[c][m]
    int c = i >> 4, m = i & 15;
    wkt[i] = wk[m * 128 + c];
  }
  for (int i = tid; i < 16384; i += nt) {         // wvt[c][o]
    int c = i >> 7, o = i & 127;
    wvt[i] = wv[o * 128 + c];
  }
}

// ---------------- pa0: merged a0 (blocks 0..2047) + prep_convb (blocks 2048..2111) ----------------
// a0 v2: coalesced 16B-unit writes; wave q owns quarter-slab q; lane-consecutive units.
__global__ __launch_bounds__(256) void pa0_kernel(const float* __restrict__ x,
                                                  unsigned short* __restrict__ xt,
                                                  const float* __restrict__ w1,
                                                  const float* __restrict__ w2,
                                                  const float* __restrict__ w3,
                                                  const float* __restrict__ w4,
                                                  const float* __restrict__ bns,
                                                  const float* __restrict__ bnb,
                                                  const float* __restrict__ bnm,
                                                  const float* __restrict__ bnv,
                                                  const float* __restrict__ wk,
                                                  const float* __restrict__ wv,
                                                  unsigned short* __restrict__ wbtr,
                                                  unsigned short* __restrict__ wvbr,
                                                  unsigned short* __restrict__ wxbr,
                                                  unsigned short* __restrict__ zrow,
                                                  float* __restrict__ bf) {
  __shared__ __align__(16) unsigned short Ts[64][136];   // 272B rows (16B-aligned)
  int t   = threadIdx.x;
  int idx = blockIdx.x;
  if (idx < 2048) {
    // ---- a0: transpose x -> xt bf16, quarter-major, pre-swizzled 16B units ----
    int b   = idx & 7;
    int px0 = (idx >> 3) * 64;
    const float* xb = x + (size_t)b * 128 * NPIX;
    int p = t & 63, cq = t >> 6;
#pragma unroll 8
    for (int i = 0; i < 32; ++i) {
      int c = cq * 32 + i;
      Ts[p][c] = f2bf(xb[(size_t)c * NPIX + px0 + p]);
    }
    __syncthreads();
    // write phase: wave q = t>>6 owns quarter q; lane u = t&63; 4 units of 16B each.
    int q = t >> 6, u = t & 63;
    unsigned short* slab = xt + ((size_t)(b * 4 + q) * 16384 + px0) * 32;
#pragma unroll
    for (int g = 0; g < 4; ++g) {
      int unit = g * 64 + u;            // 0..255, lane-consecutive -> contiguous 16B units
      int p2   = unit >> 2;             // pixel within tile
      int s    = unit & 3;              // physical slot
      int l    = s ^ ((p2 >> 1) & 3);   // logical chunk (swizzle involution)
      uint4 v = *(const uint4*)(&Ts[p2][q * 32 + l * 8]);
      *(uint4*)(slab + (size_t)unit * 8) = v;
    }
  } else {
    // ---- prep_convb (grid-stride over 64 virtual blocks) ----
    int tid = (idx - 2048) * 256 + t;
    int nt  = 64 * 256;
    for (int i = tid; i < 128; i += nt) {
      float inv = bns[i] * rsqrtf(bnv[i] + BN_EPS);
      bf[i] = bnb[i] - bnm[i] * inv;
    }
    for (int i = tid; i < 4096; i += nt) zrow[i] = 0;
    for (int i = tid; i < 16384; i += nt) {
      int e = i & 7, lane = (i >> 3) & 63, f = (i >> 9) & 7, q = i >> 12;
      int oc = f * 16 + (lane & 15);
      int c  = q * 32 + (lane >> 4) * 8 + e;
      wvbr[i] = f2bf(wv[oc * 128 + c]);
    }
    for (int i = tid; i < 6144; i += nt) {
      int e = i & 7, lane = (i >> 3) & 63, ct = i >> 9;
      int tile = ct % 3, q = ct / 3;
      int c = q * 32 + (lane >> 4) * 8 + e;
      float val;
      if (tile < 2) {
        int oc = tile * 16 + (lane & 15);
        val = w1[oc * 128 + c] * (bns[oc] * rsqrtf(bnv[oc] + BN_EPS));
      } else {
        val = wk[(lane & 15) * 128 + c];
      }
      wxbr[i] = f2bf(val);
    }
    for (int i = tid; i < 110592; i += nt) {
      int br = i / 36864;
      int r  = i - br * 36864;
      int tap  = r >> 12;
      int r2   = r & 4095;
      int q    = r2 >> 10;
      int r3   = r2 & 1023;
      int pair = r3 >> 9;
      int r4   = r3 & 511;
      int lane = r4 >> 3, e = r4 & 7;
      int oc = pair * 16 + (lane & 15);
      int c  = q * 32 + (lane >> 4) * 8 + e;
      const float* w = (br == 0) ? w2 : ((br == 1) ? w3 : w4);
      int bo = (br + 1) * 32 + oc;
      float inv = bns[bo] * rsqrtf(bnv[bo] + BN_EPS);
      wbtr[i] = f2bf(w[(oc * 128 + c) * 9 + tap] * inv);
    }
  }
}

// ---------------- prep_convf (fallback) ----------------
__global__ void prep_convf_kernel(const float* __restrict__ w2, const float* __restrict__ w3,
                                  const float* __restrict__ w4,
                                  const float* __restrict__ bns, const float* __restrict__ bnv,
                                  float* __restrict__ w24t) {
  int tid = blockIdx.x * blockDim.x + threadIdx.x;
  int nt  = gridDim.x * blockDim.x;
  for (int i = tid; i < 110592; i += nt) {
    int br  = i / 36864;
    int rem = i - br * 36864;
    int c   = rem / 288;
    int k   = (rem % 288) >> 5;
    int o   = rem & 31;
    const float* w = (br == 0) ? w2 : ((br == 1) ? w3 : w4);
    int bo = (br + 1) * 32 + o;
    float inv = bns[bo] * rsqrtf(bnv[bo] + BN_EPS);
    w24t[i] = w[(o * 128 + c) * 9 + k] * inv;
  }
}

// ---------------- a1 (fallback only) ----------------
__global__ __launch_bounds__(256) void a1_kernel(const float* __restrict__ x,
                                                 const float* __restrict__ w1f,
                                                 const float* __restrict__ wkt,
                                                 const float* __restrict__ bfp,
                                                 const float* __restrict__ bk,
                                                 float* __restrict__ out,
                                                 float* __restrict__ Kbuf) {
  __shared__ float lw1[128 * 32];
  __shared__ float lwk[128 * 16];
  __shared__ float lbf[32];
  int t = threadIdx.x;
  for (int i = t; i < 4096; i += 256) lw1[i] = w1f[i];
  for (int i = t; i < 2048; i += 256) lwk[i] = wkt[i];
  if (t < 32) lbf[t] = bfp[t];
  __syncthreads();

  int b  = blockIdx.y;
  int px = blockIdx.x * 256 + t;
  const float* xb = x + (size_t)b * 128 * NPIX;

  float acc[48];
#pragma unroll
  for (int i = 0; i < 48; ++i) acc[i] = 0.f;

  for (int c = 0; c < 128; ++c) {
    float xv = xb[(size_t)c * NPIX + px];
    const float4* w1p = (const float4*)(lw1 + c * 32);
#pragma unroll
    for (int j = 0; j < 8; ++j) {
      float4 w = w1p[j];
      acc[j*4+0] = fmaf(w.x, xv, acc[j*4+0]);
      acc[j*4+1] = fmaf(w.y, xv, acc[j*4+1]);
      acc[j*4+2] = fmaf(w.z, xv, acc[j*4+2]);
      acc[j*4+3] = fmaf(w.w, xv, acc[j*4+3]);
    }
    const float4* wkp = (const float4*)(lwk + c * 16);
#pragma unroll
    for (int j = 0; j < 4; ++j) {
      float4 w = wkp[j];
      acc[32+j*4+0] = fmaf(w.x, xv, acc[32+j*4+0]);
      acc[32+j*4+1] = fmaf(w.y, xv, acc[32+j*4+1]);
      acc[32+j*4+2] = fmaf(w.z, xv, acc[32+j*4+2]);
      acc[32+j*4+3] = fmaf(w.w, xv, acc[32+j*4+3]);
    }
  }
#pragma unroll
  for (int o = 0; o < 32; ++o)
    out[((size_t)(b * 128 + o)) * NPIX + px] = fmaxf(acc[o] + lbf[o], 0.f);
#pragma unroll
  for (int m = 0; m < 16; ++m)
    Kbuf[((size_t)(b * 16 + m)) * NPIX + px] = acc[32 + m] + bk[m];
}

// ---------------- a2m (round-11 body): 3x16KB buffers, counted-vmcnt 2-deep pipeline ----------------
__global__ __launch_bounds__(256) void a2m_kernel(const unsigned short* __restrict__ xt,
                                                  const unsigned short* __restrict__ zrow,
                                                  const unsigned short* __restrict__ wbtr,
                                                  const float* __restrict__ bfp,
                                                  float* __restrict__ out) {
  __shared__ unsigned short sx[3 * 8192 + 8];   // 3x16KB sub-buffers + 16B zero page @byte 49152
  int t    = threadIdx.x;
  int wave = t >> 6, lane = t & 63;
  int l15  = lane & 15, cg = lane >> 4;
  int idx  = blockIdx.x;
  int b    = idx & 7;                           // batch -> XCD
  int rest = idx >> 3;
  int h2   = rest & 63;
  int br   = rest >> 6;
  int d    = 6 * (br + 1);
  int h0   = h2 * 2;
  int j    = wave >> 1;                         // row of the pair this wave computes/stages
  int whalf = wave & 1;                         // px half (compute) / row half (stage)
  int p0   = whalf * 64;

  if (t == 0) *(uint4*)(sx + 24576) = make_uint4(0u, 0u, 0u, 0u);

  const unsigned short* wb    = wbtr + (size_t)br * 36864;
  const unsigned short* slabs = xt + (size_t)b * 4 * 524288;

  f32x4 acc[2][4];
#pragma unroll
  for (int i = 0; i < 2; ++i)
#pragma unroll
    for (int n = 0; n < 4; ++n) acc[i][n] = (f32x4){0.f, 0.f, 0.f, 0.f};

  int pxb[3], xorv[3];
#pragma unroll
  for (int kw = 0; kw < 3; ++kw) {
    pxb[kw]  = p0 + l15 + (kw - 1) * d;
    xorv[kw] = (cg ^ ((pxb[kw] >> 1) & 3)) << 4;
  }

  auto STAGE = [&](int s) {
    int q = s / 3, kh = s % 3;
    int srow = h0 + j + (kh - 1) * d;
    const unsigned short* rowsrc =
        ((unsigned)srow < 128u) ? (slabs + (size_t)q * 524288 + (size_t)srow * 4096)
                                : zrow;
    const unsigned short* gsrc = rowsrc + whalf * 2048 + lane * 8;
    unsigned short* lbase = sx + (s % 3) * 8192 + j * 4096 + whalf * 2048;
#pragma unroll
    for (int k = 0; k < 4; ++k)
      __builtin_amdgcn_global_load_lds((gas_ptr)(const void*)(gsrc + k * 512),
                                       (las_ptr)(void*)(lbase + k * 512), 16, 0, 0);
  };

  auto COMPUTE = [&](int s) {
    int q = s / 3, kh = s % 3;
    int bb = (s % 3) * 16384 + j * 8192;        // byte base of this wave's row
    bf16x8 a[3][2];
#pragma unroll
    for (int kw = 0; kw < 3; ++kw) {
      int tap = kh * 3 + kw;
      const unsigned short* wt = wb + ((((size_t)tap * 4 + q) * 2) << 9);
      a[kw][0] = *(const bf16x8*)(wt + lane * 8);
      a[kw][1] = *(const bf16x8*)(wt + 512 + lane * 8);
    }
#pragma unroll
    for (int kw = 0; kw < 3; ++kw) {
      int base = bb + pxb[kw] * 64 + xorv[kw];
#pragma unroll
      for (int nf = 0; nf < 4; ++nf) {
        int px   = pxb[kw] + nf * 16;
        int addr = ((unsigned)px < 128u) ? (base + nf * 1024) : 49152;
        bf16x8 bv = *(const bf16x8*)((const char*)sx + addr);
        acc[0][nf] = __builtin_amdgcn_mfma_f32_16x16x32_bf16(a[kw][0], bv, acc[0][nf], 0, 0, 0);
        acc[1][nf] = __builtin_amdgcn_mfma_f32_16x16x32_bf16(a[kw][1], bv, acc[1][nf], 0, 0, 0);
      }
    }
  };

  STAGE(0);
  STAGE(1);
  __syncthreads();                              // full drain once: buffers 0,1 ready; zero page visible
  for (int s = 0; s < 12; ++s) {
    COMPUTE(s);
    if (s < 10) STAGE(s + 2);                   // keep 2 stages in flight
    if (s < 11) {
      if (s < 10) asm volatile("s_waitcnt vmcnt(4)" ::: "memory");
      else        asm volatile("s_waitcnt vmcnt(0)" ::: "memory");
      __builtin_amdgcn_s_barrier();
      __builtin_amdgcn_sched_barrier(0);
    }
  }

  int ocb = (br + 1) * 32;
  int pxw = (h0 + j) * 128 + p0;
#pragma unroll
  for (int mf = 0; mf < 2; ++mf) {
#pragma unroll
    for (int r = 0; r < 4; ++r) {
      int oc = mf * 16 + cg * 4 + r;
      float bias = bfp[ocb + oc];
      float* op = out + ((size_t)(b * 128 + ocb + oc)) * NPIX + pxw + l15;
#pragma unroll
      for (int nf = 0; nf < 4; ++nf)
        op[nf * 16] = fmaxf(acc[mf][nf][r] + bias, 0.f);
    }
  }
}

// ---------------- a2f (fallback) ----------------
__global__ __launch_bounds__(256) void a2f_kernel(const float* __restrict__ x,
                                                  const float* __restrict__ w24t,
                                                  const float* __restrict__ bfp,
                                                  float* __restrict__ out) {
  int t  = threadIdx.x;
  int og = t & 3;
  int pg = (t >> 2) & 15;
  int r  = t >> 6;
  int br = blockIdx.z;
  int b  = blockIdx.y;
  int h  = blockIdx.x * 4 + r;
  int d  = 6 * (br + 1);

  const float* wt = w24t + (size_t)br * 36864;
  const float* bf = bfp + (br + 1) * 32;
  const float* xb = x + (size_t)b * 128 * NPIX;
  int w0 = pg << 3;

  float acc[8][8];
#pragma unroll
  for (int p = 0; p < 8; ++p)
#pragma unroll
    for (int o = 0; o < 8; ++o) acc[p][o] = 0.f;

  for (int c = 0; c < 128; ++c) {
    const float* xc = xb + (size_t)c * NPIX;
    const float* wc = wt + c * 288;
#pragma unroll
    for (int kh = 0; kh < 3; ++kh) {
      int row = h + (kh - 1) * d;
      if ((unsigned)row >= 128u) continue;
      const float* xr = xc + row * 128;
#pragma unroll
      for (int kw = 0; kw < 3; ++kw) {
        int wb = w0 + (kw - 1) * d;
        float xv[8];
        if (wb >= 0 && wb <= 120) {
          const float2* p2 = (const float2*)(xr + wb);
#pragma unroll
          for (int jj = 0; jj < 4; ++jj) {
            float2 v = p2[jj];
            xv[2*jj] = v.x; xv[2*jj+1] = v.y;
          }
        } else {
#pragma unroll
          for (int jj = 0; jj < 8; ++jj) {
            int ww = wb + jj;
            xv[jj] = ((unsigned)ww < 128u) ? xr[ww] : 0.f;
          }
        }
        const float4* wp = (const float4*)(wc + (kh * 3 + kw) * 32 + og * 8);
        float4 wa = wp[0], wbv = wp[1];
        float wr[8] = {wa.x, wa.y, wa.z, wa.w, wbv.x, wbv.y, wbv.z, wbv.w};
#pragma unroll
        for (int p = 0; p < 8; ++p)
#pragma unroll
          for (int o = 0; o < 8; ++o)
            acc[p][o] = fmaf(xv[p], wr[o], acc[p][o]);
      }
    }
  }

  int chbase = (br + 1) * 32 + og * 8;
  int n = h * 128 + w0;
#pragma unroll
  for (int o = 0; o < 8; ++o) {
    float bias = bf[og * 8 + o];
    float* op = out + ((size_t)(b * 128 + chbase + o)) * NPIX + n;
    float4 v0 = make_float4(fmaxf(acc[0][o] + bias, 0.f), fmaxf(acc[1][o] + bias, 0.f),
                            fmaxf(acc[2][o] + bias, 0.f), fmaxf(acc[3][o] + bias, 0.f));
    float4 v1 = make_float4(fmaxf(acc[4][o] + bias, 0.f), fmaxf(acc[5][o] + bias, 0.f),
                            fmaxf(acc[6][o] + bias, 0.f), fmaxf(acc[7][o] + bias, 0.f));
    ((float4*)op)[0] = v0;
    ((float4*)op)[1] = v1;
  }
}

// ---------------- cm v7: 1 tile/block, batch->XCD swizzle, swizzled-xt reads ----------------
__global__ __launch_bounds__(256) void cm_kernel(const unsigned short* __restrict__ xt,
                                                 const unsigned short* __restrict__ wvbr,
                                                 const unsigned short* __restrict__ wxbr,
                                                 const float* __restrict__ bv,
                                                 const float* __restrict__ bfp,
                                                 const float* __restrict__ bk,
                                                 float* __restrict__ out,
                                                 float* __restrict__ part1,
                                                 float* __restrict__ part2) {
  __shared__ __align__(16) unsigned short Vl[128 * 136];   // bf16 [oc][px]
  __shared__ __align__(16) unsigned short knl[16 * 136];   // bf16 [m][px]
  int t    = threadIdx.x;
  int idx  = blockIdx.x;
  int b    = idx & 7;           // batch -> XCD (1024 % 8 == 0, bijective)
  int blk  = idx >> 3;          // 0..127 == tile
  int wave = t >> 6, lane = t & 63;
  int l15  = lane & 15, cg = lane >> 4;
  int ocb  = wave * 32;
  int pbase = blk << 7;
  int cgsw = (cg ^ ((l15 >> 1) & 3)) << 3;   // swizzled-xt unit offset (ushorts)

  float bvr[2][4];
#pragma unroll
  for (int mf = 0; mf < 2; ++mf)
#pragma unroll
    for (int r = 0; r < 4; ++r) bvr[mf][r] = bv[ocb + mf * 16 + cg * 4 + r];

  float xb4[4];
#pragma unroll
  for (int r = 0; r < 4; ++r) xb4[r] = 0.f;
  if (wave == 0) {
#pragma unroll
    for (int r = 0; r < 4; ++r) xb4[r] = bfp[cg * 4 + r];
  } else if (wave == 1) {
#pragma unroll
    for (int r = 0; r < 4; ++r) xb4[r] = bfp[16 + cg * 4 + r];
  } else if (wave == 2) {
#pragma unroll
    for (int r = 0; r < 4; ++r) xb4[r] = bk[cg * 4 + r];
  }
  int xwave = (wave < 3) ? wave : 0;

  float kr[4] = {0.f, 0.f, 0.f, 0.f};
  float sv[2][4];
#pragma unroll
  for (int mf = 0; mf < 2; ++mf)
#pragma unroll
    for (int r = 0; r < 4; ++r) sv[mf][r] = 0.f;
  f32x4 am[2];
  am[0] = (f32x4){0.f,0.f,0.f,0.f};
  am[1] = (f32x4){0.f,0.f,0.f,0.f};

#pragma unroll
  for (int hf = 0; hf < 2; ++hf) {
    f32x4 vacc[2][4];
    f32x4 xacc[4];
#pragma unroll
    for (int i = 0; i < 2; ++i)
#pragma unroll
      for (int n = 0; n < 4; ++n) vacc[i][n] = (f32x4){0.f,0.f,0.f,0.f};
#pragma unroll
    for (int n = 0; n < 4; ++n) xacc[n] = (f32x4){0.f,0.f,0.f,0.f};

#pragma unroll
    for (int cc = 0; cc < 4; ++cc) {
      const unsigned short* xq = xt + ((size_t)(b * 4 + cc) * 16384 + pbase) * 32;
      bf16x8 a0 = *(const bf16x8*)(wvbr + ((cc * 8 + wave * 2 + 0) << 9) + lane * 8);
      bf16x8 a1 = *(const bf16x8*)(wvbr + ((cc * 8 + wave * 2 + 1) << 9) + lane * 8);
      bf16x8 ax = *(const bf16x8*)(wxbr + ((cc * 3 + xwave) << 9) + lane * 8);
#pragma unroll
      for (int nf = 0; nf < 4; ++nf) {
        int nfg = hf * 4 + nf;
        bf16x8 bx = *(const bf16x8*)(xq + (size_t)(nfg * 16 + l15) * 32 + cgsw);
        vacc[0][nf] = __builtin_amdgcn_mfma_f32_16x16x32_bf16(a0, bx, vacc[0][nf], 0, 0, 0);
        vacc[1][nf] = __builtin_amdgcn_mfma_f32_16x16x32_bf16(a1, bx, vacc[1][nf], 0, 0, 0);
        if (wave < 3)
          xacc[nf] = __builtin_amdgcn_mfma_f32_16x16x32_bf16(ax, bx, xacc[nf], 0, 0, 0);
      }
    }

#pragma unroll
    for (int mf = 0; mf < 2; ++mf) {
#pragma unroll
      for (int r = 0; r < 4; ++r) {
        float s = 0.f;
#pragma unroll
        for (int nf = 0; nf < 4; ++nf) s += vacc[mf][nf][r];
        sv[mf][r] += s;
        int c = ocb + mf * 16 + cg * 4 + r;
#pragma unroll
        for (int nf = 0; nf < 4; ++nf)
          Vl[c * 136 + (hf * 4 + nf) * 16 + l15] = f2bf(vacc[mf][nf][r] + bvr[mf][r]);
      }
    }

    if (wave < 2) {
#pragma unroll
      for (int r = 0; r < 4; ++r) {
        int oc = wave * 16 + cg * 4 + r;
        float* op = out + ((size_t)(b * 128 + oc)) * NPIX + pbase + l15;
#pragma unroll
        for (int nf = 0; nf < 4; ++nf)
          op[(hf * 4 + nf) * 16] = fmaxf(xacc[nf][r] + xb4[r], 0.f);
      }
    } else if (wave == 2) {
#pragma unroll
      for (int nf = 0; nf < 4; ++nf) {
        int nfg = hf * 4 + nf;
        float kq[4]; float s2 = 0.f;
#pragma unroll
        for (int r = 0; r < 4; ++r) {
          kq[r] = xacc[nf][r] + xb4[r];
          s2 = fmaf(kq[r], kq[r], s2);
        }
        s2 += __shfl_xor(s2, 16);
        s2 += __shfl_xor(s2, 32);
        float inv = rsqrtf(s2);
#pragma unroll
        for (int r = 0; r < 4; ++r) {
          float kn = kq[r] * inv;
          knl[(cg * 4 + r) * 136 + nfg * 16 + l15] = f2bf(kn);
          kr[r] += kn;
        }
      }
    }
  }
  __syncthreads();

#pragma unroll
  for (int ks = 0; ks < 4; ++ks) {
    bf16x8 af = *(const bf16x8*)(knl + l15 * 136 + ks * 32 + cg * 8);
    bf16x8 b0 = *(const bf16x8*)(Vl + (size_t)(ocb + l15) * 136 + ks * 32 + cg * 8);
    bf16x8 b1 = *(const bf16x8*)(Vl + (size_t)(ocb + 16 + l15) * 136 + ks * 32 + cg * 8);
    am[0] = __builtin_amdgcn_mfma_f32_16x16x32_bf16(af, b0, am[0], 0, 0, 0);
    am[1] = __builtin_amdgcn_mfma_f32_16x16x32_bf16(af, b1, am[1], 0, 0, 0);
  }

  float* pp = (blk < 64) ? (part1 + ((size_t)b * 64 + blk) * 2192)
                         : (part2 + ((size_t)b * 64 + (blk - 64)) * 2192);
#pragma unroll
  for (int nf2 = 0; nf2 < 2; ++nf2)
#pragma unroll
    for (int r = 0; r < 4; ++r)
      pp[(cg * 4 + r) * 128 + ocb + nf2 * 16 + l15] = am[nf2][r];
#pragma unroll
  for (int off = 1; off < 16; off <<= 1) {
#pragma unroll
    for (int mf = 0; mf < 2; ++mf)
#pragma unroll
      for (int r = 0; r < 4; ++r)
        sv[mf][r] += __shfl_xor(sv[mf][r], off);
  }
  if (l15 == 0) {
#pragma unroll
    for (int mf = 0; mf < 2; ++mf)
#pragma unroll
      for (int r = 0; r < 4; ++r) {
        int c = ocb + mf * 16 + cg * 4 + r;
        pp[2048 + c] = sv[mf][r] + 128.f * bv[c];
      }
  }
  if (wave == 2) {
#pragma unroll
    for (int off = 1; off < 16; off <<= 1) {
#pragma unroll
      for (int r = 0; r < 4; ++r)
        kr[r] += __shfl_xor(kr[r], off);
    }
    if (l15 == 0) {
#pragma unroll
      for (int r = 0; r < 4; ++r)
        pp[2048 + 128 + cg * 4 + r] = kr[r];
    }
  }
}

// ---------------- cf (fallback) ----------------
__global__ __launch_bounds__(256) void cf_kernel(const float* __restrict__ x,
                                                 const float* __restrict__ bv,
                                                 const float* __restrict__ Kbuf,
                                                 const float* __restrict__ wvt,
                                                 float* __restrict__ part) {
  __shared__ float Vl[128 * 129];
  __shared__ float knl[16 * 132];
  int t   = threadIdx.x;
  int b   = blockIdx.y;
  int blk = blockIdx.x;
  const float* Kb = Kbuf + (size_t)b * 16 * NPIX;
  const float* xb = x + (size_t)b * 128 * NPIX;

  int m_own = t & 15;
  int c0    = (t >> 4) << 3;
  int pxg   = t & 15;

  float bvr[8];
#pragma unroll
  for (int jj = 0; jj < 8; ++jj) bvr[jj] = bv[c0 + jj];

  float macc[8] = {0,0,0,0,0,0,0,0};
  float vs[8]   = {0,0,0,0,0,0,0,0};
  float ksum[16];
#pragma unroll
  for (int m = 0; m < 16; ++m) ksum[m] = 0.f;

  for (int tile = blk; tile < 128; tile += 64) {
    __syncthreads();
    int pbase = tile << 7;

    if (t < 128) {
      float kv[16]; float ss = 0.f;
#pragma unroll
      for (int m = 0; m < 16; ++m) {
        kv[m] = Kb[(size_t)m * NPIX + pbase + t];
        ss = fmaf(kv[m], kv[m], ss);
      }
      float inv = rsqrtf(ss);
#pragma unroll
      for (int m = 0; m < 16; ++m) {
        float kn = kv[m] * inv;
        knl[m * 132 + t] = kn;
        ksum[m] += kn;
      }
    }

    float v[8][8];
#pragma unroll
    for (int i = 0; i < 8; ++i)
#pragma unroll
      for (int jj = 0; jj < 8; ++jj) v[i][jj] = 0.f;
    int px0 = pbase + (pxg << 3);
    for (int k = 0; k < 128; ++k) {
      const float4* xp = (const float4*)(xb + (size_t)k * NPIX + px0);
      float4 xa = xp[0], xc4 = xp[1];
      const float4* wp = (const float4*)(wvt + k * 128 + c0);
      float4 wa = wp[0], wc4 = wp[1];
      float xv[8] = {xa.x, xa.y, xa.z, xa.w, xc4.x, xc4.y, xc4.z, xc4.w};
      float wr[8] = {wa.x, wa.y, wa.z, wa.w, wc4.x, wc4.y, wc4.z, wc4.w};
#pragma unroll
      for (int i = 0; i < 8; ++i)
#pragma unroll
        for (int jj = 0; jj < 8; ++jj)
          v[i][jj] = fmaf(wr[i], xv[jj], v[i][jj]);
    }
#pragma unroll
    for (int i = 0; i < 8; ++i)
#pragma unroll
      for (int jj = 0; jj < 8; ++jj)
        Vl[(c0 + i) * 129 + (pxg << 3) + jj] = v[i][jj] + bvr[i];
    __syncthreads();

    for (int px = 0; px < 128; ++px) {
      float knv = knl[m_own * 132 + px];
      float vv[8];
#pragma unroll
      for (int jj = 0; jj < 8; ++jj) vv[jj] = Vl[(c0 + jj) * 129 + px];
#pragma unroll
      for (int jj = 0; jj < 8; ++jj) macc[jj] = fmaf(knv, vv[jj], macc[jj]);
      if (m_own == 0) {
#pragma unroll
        for (int jj = 0; jj < 8; ++jj) vs[jj] += vv[jj];
      }
    }
  }

  int blkid = b * 64 + blk;
  float* pp = part + (size_t)blkid * 2192;
#pragma unroll
  for (int jj = 0; jj < 8; ++jj) pp[m_own * 128 + c0 + jj] = macc[jj];
  if (m_own == 0) {
#pragma unroll
    for (int jj = 0; jj < 8; ++jj) pp[2048 + c0 + jj] = vs[jj];
  }
  __syncthreads();
  if (t < 128) {
#pragma unroll
    for (int m = 0; m < 16; ++m) knl[m * 132 + t] = ksum[m];
  }
  __syncthreads();
  if (t < 16) {
    float s = 0.f;
    for (int i = 0; i < 128; ++i) s += knl[t * 132 + i];
    pp[2048 + 128 + t] = s;
  }
}

// ---------------- reduce (fallback: 64 groups) ----------------
__global__ void reduce_kernel(const float* __restrict__ part, float* __restrict__ stats) {
  int b = blockIdx.y, t = threadIdx.x;
  int e = blockIdx.x * 256 + t;
  if (e >= 2192) return;
  const float* pp = part + (size_t)b * 64 * 2192;
  float s = 0.f;
  for (int g = 0; g < 64; ++g) s += pp[(size_t)g * 2192 + e];
  stats[(size_t)b * 2192 + e] = s;
}

// ---------------- reduce2 (mfma: 64 + 64 groups) ----------------
__global__ void reduce2_kernel(const float* __restrict__ part1,
                               const float* __restrict__ part2,
                               float* __restrict__ stats) {
  int b = blockIdx.y, t = threadIdx.x;
  int e = blockIdx.x * 256 + t;
  if (e >= 2192) return;
  const float* p1 = part1 + (size_t)b * 64 * 2192;
  const float* p2 = part2 + (size_t)b * 64 * 2192;
  float s = 0.f;
  for (int g = 0; g < 64; ++g) s += p1[(size_t)g * 2192 + e];
  for (int g = 0; g < 64; ++g) s += p2[(size_t)g * 2192 + e];
  stats[(size_t)b * 2192 + e] = s;
}

// ---------------- df v2: fused final pass, c-split thread pairs (1024 blocks) ----------------
__global__ __launch_bounds__(256) void df_kernel(const float* __restrict__ stats,
                                                 const float* __restrict__ wq,
                                                 const float* __restrict__ bq,
                                                 const float* __restrict__ gamma,
                                                 float* __restrict__ out) {
  __shared__ float matl[128 * 16];
  __shared__ float wql[128 * 16];
  __shared__ float vsl[128];
  __shared__ float ksl[16];
  __shared__ float qex[16][2][128];
  int t = threadIdx.x;
  int b = blockIdx.y;
  const float* st = stats + (size_t)b * 2192;
  for (int i = t; i < 2048; i += 256) {
    int m = i >> 7, c = i & 127;
    matl[c * 16 + m] = st[i];
    wql[c * 16 + m]  = wq[m * 128 + c];
  }
  if (t < 128) vsl[t] = st[2048 + t];
  if (t < 16)  ksl[t] = st[2048 + 128 + t] + EPS_V;
  __syncthreads();

  int pxl  = t & 127, half = t >> 7;
  int px   = blockIdx.x * 128 + pxl;
  int cbeg = half * 64;
  float* ob = out + (size_t)b * 128 * NPIX;

  float q[16];
#pragma unroll
  for (int m = 0; m < 16; ++m) q[m] = (half == 0) ? bq[m] : 0.f;
  for (int c = cbeg; c < cbeg + 64; ++c) {
    float xv = ob[(size_t)c * NPIX + px];
    const float4* wp = (const float4*)(wql + c * 16);
#pragma unroll
    for (int jj = 0; jj < 4; ++jj) {
      float4 w = wp[jj];
      q[jj*4+0] = fmaf(w.x, xv, q[jj*4+0]);
      q[jj*4+1] = fmaf(w.y, xv, q[jj*4+1]);
      q[jj*4+2] = fmaf(w.z, xv, q[jj*4+2]);
      q[jj*4+3] = fmaf(w.w, xv, q[jj*4+3]);
    }
  }
#pragma unroll
  for (int m = 0; m < 16; ++m) qex[m][half][pxl] = q[m];
  __syncthreads();   // also fences: all out-reads done before any out-write below
#pragma unroll
  for (int m = 0; m < 16; ++m) q[m] = qex[m][0][pxl] + qex[m][1][pxl];

  float ss = 0.f;
#pragma unroll
  for (int m = 0; m < 16; ++m) ss = fmaf(q[m], q[m], ss);
  float inv = rsqrtf(ss);
#pragma unroll
  for (int m = 0; m < 16; ++m) q[m] *= inv;
  float den = (float)NPIX;
#pragma unroll
  for (int m = 0; m < 16; ++m) den = fmaf(q[m], ksl[m], den);
  float tl = gamma[0] / den;

  for (int c = cbeg; c < cbeg + 64; ++c) {
    float s = vsl[c];
    const float4* mp = (const float4*)(matl + c * 16);
#pragma unroll
    for (int jj = 0; jj < 4; ++jj) {
      float4 w = mp[jj];
      s = fmaf(w.x, q[jj*4+0], s);
      s = fmaf(w.y, q[jj*4+1], s);
      s = fmaf(w.z, q[jj*4+2], s);
      s = fmaf(w.w, q[jj*4+3], s);
    }
    ob[(size_t)c * NPIX + px] = tl * s;
  }
}

extern "C" void kernel_launch(void* const* d_in, const int* in_sizes, int n_in,
                              void* d_out, int out_size, void* d_ws, size_t ws_size,
                              hipStream_t stream) {
  (void)in_sizes; (void)n_in; (void)out_size;
  const float* x   = (const float*)d_in[0];
  const float* w1  = (const float*)d_in[1];
  const float* w2  = (const float*)d_in[2];
  const float* w3  = (const float*)d_in[3];
  const float* w4  = (const float*)d_in[4];
  const float* bns = (const float*)d_in[5];
  const float* bnb = (const float*)d_in[6];
  const float* bnm = (const float*)d_in[7];
  const float* bnv = (const float*)d_in[8];
  const float* wq  = (const float*)d_in[9];
  const float* bq  = (const float*)d_in[10];
  const float* wk  = (const float*)d_in[11];
  const float* bk  = (const float*)d_in[12];
  const float* wv  = (const float*)d_in[13];
  const float* bv  = (const float*)d_in[14];
  const float* gm  = (const float*)d_in[15];
  float* ws  = (float*)d_ws;
  float* out = (float*)d_out;

  float* Kbuf = ws + OFF_K;
  float* w1f  = ws + OFF_W1F;
  float* wkt  = ws + OFF_WKT;
  float* wvt  = ws + OFF_WVT;
  float* bfp  = ws + OFF_BF;
  float* part = ws + OFF_PART;
  float* stat = ws + OFF_STATS;

  bool use_mfma = ws_size >= NEW_END * sizeof(float);
  if (use_mfma) {
    unsigned short* wbtr = (unsigned short*)(ws + OFF_WBT);
    unsigned short* xt   = (unsigned short*)(ws + OFF_XT);
    unsigned short* wvbr = (unsigned short*)(ws + OFF_WVB);
    unsigned short* zrow = (unsigned short*)(ws + OFF_ZROW);
    unsigned short* wxbr = (unsigned short*)(ws + OFF_K);   // first 6144 floats of K region
    float* part2 = ws + OFF_PART2;                          // K region tail (dead in mfma path)
    pa0_kernel<<<dim3(2112), 256, 0, stream>>>(x, xt, w1, w2, w3, w4,
                                               bns, bnb, bnm, bnv, wk, wv,
                                               wbtr, wvbr, wxbr, zrow, bfp);
    a2m_kernel<<<dim3(1536), 256, 0, stream>>>(xt, zrow, wbtr, bfp, out);
    cm_kernel<<<dim3(1024), 256, 0, stream>>>(xt, wvbr, wxbr, bv, bfp, bk, out, part, part2);
    reduce2_kernel<<<dim3(9, 8), 256, 0, stream>>>(part, part2, stat);
    df_kernel<<<dim3(128, 8), 256, 0, stream>>>(stat, wq, bq, gm, out);
  } else {
    float* w24t = ws + OFF_W24T;
    prep_common_kernel<<<64, 256, 0, stream>>>(w1, bns, bnb, bnm, bnv, wk, wv,
                                               w1f, wkt, wvt, bfp);
    prep_convf_kernel<<<64, 256, 0, stream>>>(w2, w3, w4, bns, bnv, w24t);
    a1_kernel<<<dim3(64, 8), 256, 0, stream>>>(x, w1f, wkt, bfp, bk, out, Kbuf);
    a2f_kernel<<<dim3(32, 8, 3), 256, 0, stream>>>(x, w24t, bfp, out);
    cf_kernel<<<dim3(64, 8), 256, 0, stream>>>(x, bv, Kbuf, wvt, part);
    reduce_kernel<<<dim3(9, 8), 256, 0, stream>>>(part, stat);
    df_kernel<<<dim3(128, 8), 256, 0, stream>>>(stat, wq, bq, gm, out);
  }
}